// Round 1
// baseline (1128.085 us; speedup 1.0000x reference)
//
#include <hip/hip_runtime.h>
#include <math.h>

// ---------------- dims ----------------
constexpr int BATCH = 32;
constexpr int C     = 512;
constexpr int CM    = 128;
constexpr int KW    = 64;     // codewords
constexpr int NPIX  = 1024;   // 32*32

#define TILE 128
#define BK 16

__device__ __forceinline__ float4 ld4(const float* p) {
    return *reinterpret_cast<const float4*>(p);
}

// ---------------------------------------------------------------------------
// Generic 128x128-tile fp32 GEMM: out[b,co,n] = relu?(scale[co]*acc + bias[co])
// A: AKMAJOR ? (K,Co) row-major : (Co,K) row-major
// BMODE 0: B[k][n] = Bsrc[b*K*NPIX + k*NPIX + n]          (1x1 conv)
// BMODE 1: 3x3 conv gather from h1 (B,CM,32,32), k = tap*128+ci
// BMODE 2: concat-K: k<CM from Bsrc (B,CM,NPIX), else from B2 (B,C,NPIX)
// ---------------------------------------------------------------------------
template<int BMODE, bool AKMAJOR, bool RELU>
__global__ __launch_bounds__(256)
void gemm_k(const float* __restrict__ A, const float* __restrict__ Bsrc,
            const float* __restrict__ B2, float* __restrict__ out,
            const float* __restrict__ scale, const float* __restrict__ bias,
            int Co, int K)
{
    const int b   = blockIdx.z;
    const int n0  = blockIdx.x * TILE;
    const int co0 = blockIdx.y * TILE;
    const int t   = threadIdx.x;
    const int tc  = t & 15;   // n sub-group
    const int tr  = t >> 4;   // co sub-group

    __shared__ float As[BK][TILE + 4];
    __shared__ float Bs[BK][TILE + 4];

    float acc[8][8];
#pragma unroll
    for (int i = 0; i < 8; ++i)
#pragma unroll
        for (int j = 0; j < 8; ++j) acc[i][j] = 0.f;

    for (int k0 = 0; k0 < K; k0 += BK) {
        // ---- A tile ----
        if (AKMAJOR) {
#pragma unroll
            for (int j = 0; j < 2; ++j) {
                int idx4 = t + 256 * j;           // 0..511 float4s
                int kk = idx4 >> 5;               // 0..15
                int c4 = idx4 & 31;               // 0..31
                float4 v = ld4(A + (size_t)(k0 + kk) * Co + co0 + c4 * 4);
                *reinterpret_cast<float4*>(&As[kk][c4 * 4]) = v;
            }
        } else {
#pragma unroll
            for (int j = 0; j < 2; ++j) {
                int idx4 = t + 256 * j;
                int row = idx4 >> 2;              // 0..127 (co)
                int kq  = idx4 & 3;
                float4 v = ld4(A + (size_t)(co0 + row) * K + k0 + kq * 4);
                As[kq * 4 + 0][row] = v.x;
                As[kq * 4 + 1][row] = v.y;
                As[kq * 4 + 2][row] = v.z;
                As[kq * 4 + 3][row] = v.w;
            }
        }
        // ---- B tile ----
        if (BMODE == 1) {
#pragma unroll
            for (int j = 0; j < 8; ++j) {
                int idx = t + 256 * j;            // 0..2047
                int kk = idx >> 7;
                int nn = idx & 127;
                int k  = k0 + kk;
                int ci = k & 127;
                int tap = k >> 7;
                int dy = tap / 3 - 1;
                int dx = tap % 3 - 1;
                int n = n0 + nn;
                int y = (n >> 5) + dy;
                int x = (n & 31) + dx;
                float v = 0.f;
                if ((unsigned)y < 32u && (unsigned)x < 32u)
                    v = Bsrc[(size_t)b * CM * NPIX + (size_t)ci * NPIX + y * 32 + x];
                Bs[kk][nn] = v;
            }
        } else {
#pragma unroll
            for (int j = 0; j < 2; ++j) {
                int idx4 = t + 256 * j;
                int kk = idx4 >> 5;
                int n4 = idx4 & 31;
                int k  = k0 + kk;
                const float* src;
                if (BMODE == 2) {
                    src = (k < CM) ? (Bsrc + (size_t)b * CM * NPIX + (size_t)k * NPIX)
                                   : (B2   + (size_t)b * C  * NPIX + (size_t)(k - CM) * NPIX);
                } else {
                    src = Bsrc + (size_t)b * K * NPIX + (size_t)k * NPIX;
                }
                float4 v = ld4(src + n0 + n4 * 4);
                *reinterpret_cast<float4*>(&Bs[kk][n4 * 4]) = v;
            }
        }
        __syncthreads();
#pragma unroll
        for (int kk = 0; kk < BK; ++kk) {
            float4 a0 = *reinterpret_cast<float4*>(&As[kk][tr * 4]);
            float4 a1 = *reinterpret_cast<float4*>(&As[kk][64 + tr * 4]);
            float4 b0 = *reinterpret_cast<float4*>(&Bs[kk][tc * 4]);
            float4 b1 = *reinterpret_cast<float4*>(&Bs[kk][64 + tc * 4]);
            float av[8] = {a0.x, a0.y, a0.z, a0.w, a1.x, a1.y, a1.z, a1.w};
            float bv[8] = {b0.x, b0.y, b0.z, b0.w, b1.x, b1.y, b1.z, b1.w};
#pragma unroll
            for (int i = 0; i < 8; ++i)
#pragma unroll
                for (int j = 0; j < 8; ++j)
                    acc[i][j] = fmaf(av[i], bv[j], acc[i][j]);
        }
        __syncthreads();
    }
    // ---- epilogue: scale/bias (+relu), vectorized store ----
#pragma unroll
    for (int i = 0; i < 8; ++i) {
        int mo = (i < 4) ? (tr * 4 + i) : (64 + tr * 4 + i - 4);
        int co = co0 + mo;
        float s  = scale ? scale[co] : 1.f;
        float bi = bias  ? bias[co]  : 0.f;
        float vals[8];
#pragma unroll
        for (int j = 0; j < 8; ++j) {
            float v = acc[i][j] * s + bi;
            if (RELU) v = fmaxf(v, 0.f);
            vals[j] = v;
        }
        float* op = out + (size_t)b * Co * NPIX + (size_t)co * NPIX + n0;
        *reinterpret_cast<float4*>(op + tc * 4)      = make_float4(vals[0], vals[1], vals[2], vals[3]);
        *reinterpret_cast<float4*>(op + 64 + tc * 4) = make_float4(vals[4], vals[5], vals[6], vals[7]);
    }
}

// ---------------- x2[b,n] = sum_c e^2 ----------------
__global__ __launch_bounds__(256)
void x2_k(const float* __restrict__ e, float* __restrict__ x2)
{
    int g = blockIdx.x * 256 + threadIdx.x;   // 0..32767
    int b = g >> 10, n = g & 1023;
    const float* p = e + (size_t)b * C * NPIX + n;
    float s = 0.f;
    for (int c = 0; c < C; ++c) {
        float v = p[(size_t)c * NPIX];
        s = fmaf(v, v, s);
    }
    x2[g] = s;
}

// ---------------- softmax over K=64 codewords ----------------
__global__ __launch_bounds__(256)
void softmax_k(const float* __restrict__ xc, const float* __restrict__ x2,
               const float* __restrict__ scale, const float* __restrict__ c2,
               float* __restrict__ a)
{
    int g = blockIdx.x * 256 + threadIdx.x;   // B*N
    int b = g >> 10, n = g & 1023;
    float xv = x2[g];
    float l[KW];
    float m = -1e30f;
#pragma unroll
    for (int k = 0; k < KW; ++k) {
        float v = scale[k] * (xv - 2.f * xc[(size_t)b * CM * NPIX + (size_t)k * NPIX + n] + c2[k]);
        l[k] = v;
        m = fmaxf(m, v);
    }
    float s = 0.f;
#pragma unroll
    for (int k = 0; k < KW; ++k) { l[k] = __expf(l[k] - m); s += l[k]; }
    float inv = 1.f / s;
#pragma unroll
    for (int k = 0; k < KW; ++k)
        a[(size_t)b * KW * NPIX + (size_t)k * NPIX + n] = l[k] * inv;
}

// ------------- enc GEMM (64x128 c-tile, K=1024 pixels) + asum + BN + mean_k -------------
__global__ __launch_bounds__(256)
void enc_k(const float* __restrict__ a, const float* __restrict__ e,
           const float* __restrict__ cw, const float* __restrict__ sK,
           const float* __restrict__ bK, float* __restrict__ en)
{
    const int b  = blockIdx.z;
    const int c0 = blockIdx.x * 128;
    const int t  = threadIdx.x;
    const int tk  = t & 15;    // k = tk*4 + i
    const int tcg = t >> 4;    // c = c0 + tcg*8 + j

    __shared__ float As[16][KW + 4];   // [nn][k]
    __shared__ float et[128][17];      // [cc][nn]
    __shared__ float asum_s[KW];
    __shared__ float en_s[16][128];

    float acc[4][8];
#pragma unroll
    for (int i = 0; i < 4; ++i)
#pragma unroll
        for (int j = 0; j < 8; ++j) acc[i][j] = 0.f;
    float asum_r = 0.f;

    for (int n0 = 0; n0 < NPIX; n0 += 16) {
#pragma unroll
        for (int j = 0; j < 4; ++j) {
            int idx = t + 256 * j;             // 0..1023
            int k = idx >> 4, nn = idx & 15;
            As[nn][k] = a[(size_t)b * KW * NPIX + (size_t)k * NPIX + n0 + nn];
        }
#pragma unroll
        for (int j = 0; j < 8; ++j) {
            int idx = t + 256 * j;             // 0..2047
            int cc = idx >> 4, nn = idx & 15;
            et[cc][nn] = e[(size_t)b * C * NPIX + (size_t)(c0 + cc) * NPIX + n0 + nn];
        }
        __syncthreads();
        if (t < KW) {
#pragma unroll
            for (int nn = 0; nn < 16; ++nn) asum_r += As[nn][t];
        }
#pragma unroll
        for (int nn = 0; nn < 16; ++nn) {
            float4 av = *reinterpret_cast<float4*>(&As[nn][tk * 4]);
            float avv[4] = {av.x, av.y, av.z, av.w};
#pragma unroll
            for (int j = 0; j < 8; ++j) {
                float ev = et[tcg * 8 + j][nn];
#pragma unroll
                for (int i = 0; i < 4; ++i)
                    acc[i][j] = fmaf(avv[i], ev, acc[i][j]);
            }
        }
        __syncthreads();
    }
    if (t < KW) asum_s[t] = asum_r;
    __syncthreads();

    float pe[8];
#pragma unroll
    for (int j = 0; j < 8; ++j) pe[j] = 0.f;
#pragma unroll
    for (int i = 0; i < 4; ++i) {
        int k = tk * 4 + i;
        float as = asum_s[k];
        float sk = sK[k], bk = bK[k];
#pragma unroll
        for (int j = 0; j < 8; ++j) {
            int c = c0 + tcg * 8 + j;
            float v = acc[i][j] - as * cw[(size_t)k * C + c];
            v = fmaxf(fmaf(v, sk, bk), 0.f);
            pe[j] += v;
        }
    }
#pragma unroll
    for (int j = 0; j < 8; ++j) en_s[tk][tcg * 8 + j] = pe[j];
    __syncthreads();
    if (t < 128) {
        float s = 0.f;
#pragma unroll
        for (int g = 0; g < 16; ++g) s += en_s[g][t];
        en[(size_t)b * C + c0 + t] = s * (1.f / 64.f);
    }
}

// ---------------- SE gate: gam = sigmoid(en @ fc_w^T + fc_b) ----------------
__global__ __launch_bounds__(256)
void gam_k(const float* __restrict__ en, const float* __restrict__ fcw,
           const float* __restrict__ fcb, float* __restrict__ gam)
{
    int b = blockIdx.x;
    int c = blockIdx.y * 256 + threadIdx.x;
    __shared__ float es[C];
    es[threadIdx.x]       = en[(size_t)b * C + threadIdx.x];
    es[threadIdx.x + 256] = en[(size_t)b * C + threadIdx.x + 256];
    __syncthreads();
    float s = fcb[c];
    const float* w = fcw + (size_t)c * C;
    for (int i = 0; i < C; i += 4) {
        float4 wv = ld4(w + i);
        s = fmaf(es[i], wv.x, s);
        s = fmaf(es[i + 1], wv.y, s);
        s = fmaf(es[i + 2], wv.z, s);
        s = fmaf(es[i + 3], wv.w, s);
    }
    gam[(size_t)b * C + c] = 1.f / (1.f + __expf(-s));
}

// ---------------- final: out = relu(xb * (1 + gam)) ----------------
__global__ __launch_bounds__(256)
void final_k(const float* __restrict__ xb, const float* __restrict__ gam,
             float* __restrict__ out)
{
    int i4 = blockIdx.x * 256 + threadIdx.x;  // 4,194,304 float4s
    size_t flat = (size_t)i4 * 4;
    int b = (int)(flat >> 19);
    int c = (int)((flat >> 10) & 511);
    float g = 1.f + gam[b * C + c];
    float4 v = ld4(xb + flat);
    float4 o = make_float4(fmaxf(v.x * g, 0.f), fmaxf(v.y * g, 0.f),
                           fmaxf(v.z * g, 0.f), fmaxf(v.w * g, 0.f));
    *reinterpret_cast<float4*>(out + flat) = o;
}

// ---------------- weight prep ----------------
__global__ void prep_small_k(const float* bn1g, const float* bn2g, const float* bn3b,
                             const float* rbnb, const float* lvcbng,
                             const float* enbng, const float* cw,
                             float* s1, float* s2, float* slvc, float* bcat,
                             float* sK, float* c2)
{
    int t = threadIdx.x;  // 1 block x 512
    const float invCB  = rsqrtf(1.f + 1e-6f);
    const float invLVC = rsqrtf(1.f + 1e-5f);
    if (t < 128) { s1[t] = bn1g[t] * invCB; s2[t] = bn2g[t] * invCB; }
    if (t < 512) { slvc[t] = lvcbng[t] * invLVC; bcat[t] = bn3b[t] + rbnb[t]; }
    if (t < 64) {
        sK[t] = enbng[t] * invLVC;
        float s = 0.f;
        for (int c = 0; c < C; ++c) s = fmaf(cw[t * C + c], cw[t * C + c], s);
        c2[t] = s;
    }
}

__global__ void prep_w2t_k(const float* __restrict__ w2, float* __restrict__ w2t)
{
    int id = blockIdx.x * 256 + threadIdx.x;  // 1152*128
    int k = id >> 7, co = id & 127;
    int ci = k & 127, tap = k >> 7;
    w2t[id] = w2[(size_t)co * (CM * 9) + ci * 9 + tap];
}

__global__ void prep_wcat_k(const float* __restrict__ c3w, const float* __restrict__ rcw,
                            const float* __restrict__ bn3g, const float* __restrict__ rbng,
                            float* __restrict__ wcat)
{
    int id = blockIdx.x * 256 + threadIdx.x;  // 640*512
    int k = id >> 9, co = id & 511;
    const float invCB = rsqrtf(1.f + 1e-6f);
    float v;
    if (k < CM) v = c3w[(size_t)co * CM + k] * (bn3g[co] * invCB);
    else        v = rcw[(size_t)co * C + (k - CM)] * (rbng[co] * invCB);
    wcat[id] = v;
}

__global__ void prep_cwpad_k(const float* __restrict__ cw, float* __restrict__ cwP)
{
    int id = blockIdx.x * 256 + threadIdx.x;  // 128*512
    int row = id >> 9;
    cwP[id] = (row < KW) ? cw[id] : 0.f;
}

// ---------------------------------------------------------------------------
extern "C" void kernel_launch(void* const* d_in, const int* in_sizes, int n_in,
                              void* d_out, int out_size, void* d_ws, size_t ws_size,
                              hipStream_t stream)
{
    const float* x      = (const float*)d_in[0];
    const float* c1w    = (const float*)d_in[1];
    const float* bn1g   = (const float*)d_in[2];
    const float* bn1b   = (const float*)d_in[3];
    const float* c2w    = (const float*)d_in[4];
    const float* bn2g   = (const float*)d_in[5];
    const float* bn2b   = (const float*)d_in[6];
    const float* c3w    = (const float*)d_in[7];
    const float* bn3g   = (const float*)d_in[8];
    const float* rcw    = (const float*)d_in[10];
    const float* rbng   = (const float*)d_in[11];
    const float* rbnb   = (const float*)d_in[12];
    const float* bn3b   = (const float*)d_in[9];
    const float* lvcw   = (const float*)d_in[13];
    const float* lvcbng = (const float*)d_in[14];
    const float* lvcbnb = (const float*)d_in[15];
    const float* cw     = (const float*)d_in[16];
    const float* scale  = (const float*)d_in[17];
    const float* enbng  = (const float*)d_in[18];
    const float* enbnb  = (const float*)d_in[19];
    const float* fcw    = (const float*)d_in[20];
    const float* fcb    = (const float*)d_in[21];
    float* out = (float*)d_out;
    float* ws  = (float*)d_ws;

    // workspace layout (floats) — total ~42.55M floats ≈ 162.3 MiB
    float* h1   = ws;                  // 4,194,304 (B,CM,N)  -> later reused as xcPad
    float* h2   = ws + 4194304;        // 4,194,304 (B,CM,N)  -> later reused as a
    float* xb   = ws + 8388608;        // 16,777,216 (B,C,N)
    float* e    = ws + 25165824;       // 16,777,216 (B,C,N)
    float* w2t  = ws + 41943040;       // 147,456   (1152,128) k-major
    float* wcat = ws + 42090496;       // 327,680   (640,512)  k-major, BN-folded
    float* cwP  = ws + 42418176;       // 65,536    (128,512)  zero-padded codewords
    float* x2   = ws + 42483712;       // 32,768
    float* en   = ws + 42516480;       // 16,384
    float* gam  = ws + 42532864;       // 16,384
    float* s1   = ws + 42549248;       // small arrays
    float* s2   = s1 + 128;
    float* slvc = s2 + 128;
    float* bcat = slvc + 512;
    float* sK   = bcat + 512;
    float* c2   = sK + 64;
    float* xcP  = h1;   // (B,128,N), rows 64..127 unused
    float* a    = h2;   // (B,64,N)

    // weight prep (tiny)
    prep_small_k<<<1, 512, 0, stream>>>(bn1g, bn2g, bn3b, rbnb, lvcbng, enbng, cw,
                                        s1, s2, slvc, bcat, sK, c2);
    prep_w2t_k<<<576, 256, 0, stream>>>(c2w, w2t);
    prep_wcat_k<<<1280, 256, 0, stream>>>(c3w, rcw, bn3g, rbng, wcat);
    prep_cwpad_k<<<256, 256, 0, stream>>>(cw, cwP);

    // conv1 + bn1 + relu : h1
    gemm_k<0, false, true><<<dim3(8, 1, 32), 256, 0, stream>>>(c1w, x, nullptr, h1, s1, bn1b, CM, C);
    // conv2 (3x3) + bn2 + relu : h2
    gemm_k<1, true, true><<<dim3(8, 1, 32), 256, 0, stream>>>(w2t, h1, nullptr, h2, s2, bn2b, CM, CM * 9);
    // conv3+bn3 + residual-conv+bn, fused concat-K GEMM, + relu : xb
    gemm_k<2, true, true><<<dim3(8, 4, 32), 256, 0, stream>>>(wcat, h2, x, xb, nullptr, bcat, C, CM + C);
    // lvc conv + bn + relu : e
    gemm_k<0, false, true><<<dim3(8, 4, 32), 256, 0, stream>>>(lvcw, xb, nullptr, e, slvc, lvcbnb, C, C);
    // encoding
    x2_k<<<128, 256, 0, stream>>>(e, x2);
    gemm_k<0, false, false><<<dim3(8, 1, 32), 256, 0, stream>>>(cwP, e, nullptr, xcP, nullptr, nullptr, CM, C);
    softmax_k<<<128, 256, 0, stream>>>(xcP, x2, scale, c2, a);
    enc_k<<<dim3(4, 1, 32), 256, 0, stream>>>(a, e, cw, sK, enbnb, en);
    gam_k<<<dim3(32, 2), 256, 0, stream>>>(en, fcw, fcb, gam);
    // out = relu(xb * (1+gam))
    final_k<<<16384, 256, 0, stream>>>(xb, gam, out);
}

// Round 2
// 524.727 us; speedup vs baseline: 2.1499x; 2.1499x over previous
//
#include <hip/hip_runtime.h>
#include <math.h>

constexpr int BATCH = 32;
constexpr int C     = 512;
constexpr int CM    = 128;
constexpr int KW    = 64;
constexpr int NPIX  = 1024;

typedef unsigned short u16;
typedef __attribute__((ext_vector_type(8))) short bf16x8;
typedef __attribute__((ext_vector_type(4))) float f32x4;
typedef __attribute__((ext_vector_type(4))) unsigned short u16x4;
typedef __attribute__((ext_vector_type(8))) unsigned short u16x8;

__device__ __forceinline__ float bf2f(u16 u) {
    unsigned int v = ((unsigned int)u) << 16;
    return __uint_as_float(v);
}
__device__ __forceinline__ u16 f2bf(float f) {
    unsigned int u = __float_as_uint(f);
    u = u + 0x7FFFu + ((u >> 16) & 1u);   // RNE
    return (u16)(u >> 16);
}
__device__ __forceinline__ float4 ld4(const float* p) {
    return *reinterpret_cast<const float4*>(p);
}
__device__ __forceinline__ void gload16(const u16* g, u16* l) {
    __builtin_amdgcn_global_load_lds((const __attribute__((address_space(1))) void*)g,
                                     (__attribute__((address_space(3))) void*)l, 16, 0, 0);
}

// ---------------------------------------------------------------------------
// NHWC bf16 MFMA GEMM: out[b][n][co] = act(scale[co]*(sum_k A[b][n][k] W[co][k]) + bias[co])
// MODE 0: A1 is (B,NPIX,K) bf16
// MODE 1: 3x3 conv: k = tap*128+ci over A1 (B,NPIX,128); OOB -> zbuf
// MODE 2: concat-K: k<128 from A1 (B,NPIX,128), else A2 (B,NPIX,512)
// ---------------------------------------------------------------------------
template<int MODE, bool RELU, bool WF32, bool WB16>
__global__ __launch_bounds__(256)
void gemm_mfma(const u16* __restrict__ A1, const u16* __restrict__ A2,
               const u16* __restrict__ Wm, float* __restrict__ outF,
               u16* __restrict__ outB, const float* __restrict__ scale,
               const float* __restrict__ bias, const u16* __restrict__ zbuf,
               int K, int Cout)
{
    __shared__ __align__(16) u16 As[4096];   // 128 rows x 32 k, chunk(g,r) at (g*128+r)*8
    __shared__ __align__(16) u16 Bs[4096];
    const int b   = blockIdx.z;
    const int n0  = blockIdx.x * 128;
    const int co0 = blockIdx.y * 128;
    const int t    = threadIdx.x;
    const int lane = t & 63;
    const int w    = t >> 6;
    const int wr = w >> 1, wc = w & 1;
    const int lhi = lane >> 4, llo = lane & 15;

    f32x4 acc[4][4];
#pragma unroll
    for (int i = 0; i < 4; ++i)
#pragma unroll
        for (int j = 0; j < 4; ++j) acc[i][j] = (f32x4){0.f, 0.f, 0.f, 0.f};

    const int aBase = lhi * 128 + wr * 64 + llo;
    const int bBase = lhi * 128 + wc * 64 + llo;

    for (int k0 = 0; k0 < K; k0 += 32) {
#pragma unroll
        for (int rd = 0; rd < 2; ++rd) {
            int ch = t + rd * 256;           // chunk id 0..511
            int g  = ch >> 7, r = ch & 127;
            int kg = k0 + g * 8;
            const u16* src;
            if (MODE == 0) {
                src = A1 + ((size_t)((b << 10) + n0 + r)) * (size_t)K + kg;
            } else if (MODE == 1) {
                int tap = kg >> 7, ci = kg & 127;
                int n = n0 + r;
                int y = (n >> 5) + tap / 3 - 1;
                int x = (n & 31) + tap % 3 - 1;
                src = ((unsigned)y < 32u && (unsigned)x < 32u)
                    ? A1 + ((size_t)((b << 10) + y * 32 + x)) * 128 + ci
                    : zbuf;
            } else {
                src = (kg < 128)
                    ? A1 + ((size_t)((b << 10) + n0 + r)) * 128 + kg
                    : A2 + ((size_t)((b << 10) + n0 + r)) * 512 + (kg - 128);
            }
            gload16(src, &As[ch * 8]);
            const u16* wsrc = Wm + (size_t)(co0 + r) * (size_t)K + kg;
            gload16(wsrc, &Bs[ch * 8]);
        }
        __syncthreads();
        const bf16x8* Av = (const bf16x8*)As;
        const bf16x8* Bv = (const bf16x8*)Bs;
        bf16x8 af[4], bfr[4];
#pragma unroll
        for (int m = 0; m < 4; ++m)  af[m]  = Av[aBase + m * 16];
#pragma unroll
        for (int nf = 0; nf < 4; ++nf) bfr[nf] = Bv[bBase + nf * 16];
#pragma unroll
        for (int m = 0; m < 4; ++m)
#pragma unroll
            for (int nf = 0; nf < 4; ++nf)
                acc[m][nf] = __builtin_amdgcn_mfma_f32_16x16x32_bf16(af[m], bfr[nf], acc[m][nf], 0, 0, 0);
        __syncthreads();
    }
#pragma unroll
    for (int nf = 0; nf < 4; ++nf) {
        int coL = co0 + wc * 64 + nf * 16 + llo;
        float s  = scale ? scale[coL] : 1.f;
        float bi = bias  ? bias[coL]  : 0.f;
#pragma unroll
        for (int m = 0; m < 4; ++m) {
            f32x4 v = acc[m][nf];
#pragma unroll
            for (int q = 0; q < 4; ++q) {
                int row = n0 + wr * 64 + m * 16 + lhi * 4 + q;
                float val = fmaf(v[q], s, bi);
                if (RELU) val = fmaxf(val, 0.f);
                size_t off = ((size_t)((b << 10) + row)) * (size_t)Cout + coL;
                if (WF32) outF[off] = val;
                if (WB16) outB[off] = f2bf(val);
            }
        }
    }
}

// ---------------- NCHW f32 -> NHWC bf16 ----------------
__global__ __launch_bounds__(256)
void tr_in_k(const float* __restrict__ x, u16* __restrict__ xbf)
{
    __shared__ float tile[64][65];
    int b = blockIdx.z, n0 = blockIdx.x * 64, c0 = blockIdx.y * 64, t = threadIdx.x;
#pragma unroll
    for (int q = 0; q < 16; ++q) {
        int idx = t + 256 * q;
        int c = idx >> 6, n = idx & 63;
        tile[c][n] = x[((size_t)((b << 9) + c0 + c) << 10) + n0 + n];
    }
    __syncthreads();
#pragma unroll
    for (int q = 0; q < 16; ++q) {
        int idx = t + 256 * q;
        int nn = idx >> 6, cc = idx & 63;
        xbf[((size_t)((b << 10) + n0 + nn) << 9) + c0 + cc] = f2bf(tile[cc][nn]);
    }
}

// ---------------- final: out(NCHW) = relu(xb_nhwc*(1+gam)) ----------------
__global__ __launch_bounds__(256)
void final_tr_k(const float* __restrict__ xb, const float* __restrict__ gam,
                float* __restrict__ out)
{
    __shared__ float tile[64][65];
    int b = blockIdx.z, n0 = blockIdx.x * 64, c0 = blockIdx.y * 64, t = threadIdx.x;
#pragma unroll
    for (int q = 0; q < 16; ++q) {
        int idx = t + 256 * q;
        int n = idx >> 6, c = idx & 63;
        float g = 1.f + gam[(b << 9) + c0 + c];
        float v = xb[((size_t)((b << 10) + n0 + n) << 9) + c0 + c] * g;
        tile[n][c] = fmaxf(v, 0.f);
    }
    __syncthreads();
#pragma unroll
    for (int q = 0; q < 16; ++q) {
        int idx = t + 256 * q;
        int cc = idx >> 6, nn = idx & 63;
        out[((size_t)((b << 9) + c0 + cc) << 10) + n0 + nn] = tile[nn][cc];
    }
}

// ---------------- x2[b,n] = sum_c e^2 (one wave per row) ----------------
__global__ __launch_bounds__(256)
void x2_k(const u16* __restrict__ e, float* __restrict__ x2)
{
    int w = threadIdx.x >> 6, lane = threadIdx.x & 63;
    int g = blockIdx.x * 4 + w;
    u16x8 v = *(const u16x8*)(e + ((size_t)g << 9) + lane * 8);
    float s = 0.f;
#pragma unroll
    for (int j = 0; j < 8; ++j) { float f = bf2f(v[j]); s = fmaf(f, f, s); }
#pragma unroll
    for (int off = 32; off > 0; off >>= 1) s += __shfl_xor(s, off, 64);
    if (lane == 0) x2[g] = s;
}

// ---------------- softmax over K=64 (NHWC rows) ----------------
__global__ __launch_bounds__(256)
void softmax_k(const u16* __restrict__ xc, const float* __restrict__ x2,
               const float* __restrict__ scale, const float* __restrict__ c2,
               u16* __restrict__ a)
{
    __shared__ float sc_s[64], c2_s[64];
    int t = threadIdx.x;
    if (t < 64) { sc_s[t] = scale[t]; c2_s[t] = c2[t]; }
    __syncthreads();
    int g = blockIdx.x * 256 + t;
    float xv = x2[g];
    const u16* xp = xc + ((size_t)g << 7);
    float l[64];
    float m = -1e30f;
#pragma unroll
    for (int k0 = 0; k0 < 64; k0 += 8) {
        u16x8 v = *(const u16x8*)(xp + k0);
#pragma unroll
        for (int j = 0; j < 8; ++j) {
            int k = k0 + j;
            float lv = sc_s[k] * (xv - 2.f * bf2f(v[j]) + c2_s[k]);
            l[k] = lv; m = fmaxf(m, lv);
        }
    }
    float ssum = 0.f;
#pragma unroll
    for (int k = 0; k < 64; ++k) { float ev = __expf(l[k] - m); l[k] = ev; ssum += ev; }
    float inv = 1.f / ssum;
    u16* ap = a + ((size_t)g << 6);
#pragma unroll
    for (int k0 = 0; k0 < 64; k0 += 8) {
        u16x8 o;
#pragma unroll
        for (int j = 0; j < 8; ++j) o[j] = f2bf(l[k0 + j] * inv);
        *(u16x8*)(ap + k0) = o;
    }
}

// ------------- enc (fp32 outer-product over n) + asum + BN + mean_k -------------
__global__ __launch_bounds__(256)
void enc_k(const u16* __restrict__ a, const u16* __restrict__ e,
           const float* __restrict__ cw, const float* __restrict__ sK,
           const float* __restrict__ bK, float* __restrict__ en)
{
    const int b = blockIdx.y, c0 = blockIdx.x * 128, t = threadIdx.x;
    const int kq = t >> 4, cs = t & 15;
    __shared__ float a_sf[16][68];
    __shared__ float e_sf[16][132];
    __shared__ float asum_s[64];
    __shared__ float en_s[16][128];
    float acc[4][8];
#pragma unroll
    for (int i = 0; i < 4; ++i)
#pragma unroll
        for (int j = 0; j < 8; ++j) acc[i][j] = 0.f;
    float asum_r = 0.f;
    const int nnL = t >> 4, k4 = (t & 15) * 4, c8 = (t & 15) * 8;

    for (int n0 = 0; n0 < NPIX; n0 += 16) {
        u16x4 va = *(const u16x4*)(a + (((size_t)((b << 10) + n0 + nnL)) << 6) + k4);
        a_sf[nnL][k4 + 0] = bf2f(va.x); a_sf[nnL][k4 + 1] = bf2f(va.y);
        a_sf[nnL][k4 + 2] = bf2f(va.z); a_sf[nnL][k4 + 3] = bf2f(va.w);
        u16x8 ve = *(const u16x8*)(e + (((size_t)((b << 10) + n0 + nnL)) << 9) + c0 + c8);
#pragma unroll
        for (int j = 0; j < 8; ++j) e_sf[nnL][c8 + j] = bf2f(ve[j]);
        __syncthreads();
        if (t < 64) {
#pragma unroll
            for (int nn = 0; nn < 16; ++nn) asum_r += a_sf[nn][t];
        }
#pragma unroll
        for (int nn = 0; nn < 16; ++nn) {
            float4 av = ld4(&a_sf[nn][kq * 4]);
            float4 e0 = ld4(&e_sf[nn][cs * 8]);
            float4 e1 = ld4(&e_sf[nn][cs * 8 + 4]);
            float avv[4] = {av.x, av.y, av.z, av.w};
            float evv[8] = {e0.x, e0.y, e0.z, e0.w, e1.x, e1.y, e1.z, e1.w};
#pragma unroll
            for (int i = 0; i < 4; ++i)
#pragma unroll
                for (int j = 0; j < 8; ++j)
                    acc[i][j] = fmaf(avv[i], evv[j], acc[i][j]);
        }
        __syncthreads();
    }
    if (t < 64) asum_s[t] = asum_r;
    __syncthreads();
    float pe8[8];
#pragma unroll
    for (int j = 0; j < 8; ++j) pe8[j] = 0.f;
#pragma unroll
    for (int i = 0; i < 4; ++i) {
        int k = kq * 4 + i;
        float as = asum_s[k], sk = sK[k], bk = bK[k];
#pragma unroll
        for (int j = 0; j < 8; ++j) {
            int c = c0 + cs * 8 + j;
            float v = acc[i][j] - as * cw[((size_t)k << 9) + c];
            pe8[j] += fmaxf(fmaf(v, sk, bk), 0.f);
        }
    }
#pragma unroll
    for (int j = 0; j < 8; ++j) en_s[kq][cs * 8 + j] = pe8[j];
    __syncthreads();
    if (t < 128) {
        float s = 0.f;
#pragma unroll
        for (int g = 0; g < 16; ++g) s += en_s[g][t];
        en[(size_t)(b << 9) + c0 + t] = s * (1.f / 64.f);
    }
}

// ---------------- SE gate ----------------
__global__ __launch_bounds__(256)
void gam_k(const float* __restrict__ en, const float* __restrict__ fcw,
           const float* __restrict__ fcb, float* __restrict__ gam)
{
    int b = blockIdx.x;
    int c = blockIdx.y * 256 + threadIdx.x;
    __shared__ float es[C];
    es[threadIdx.x]       = en[(size_t)b * C + threadIdx.x];
    es[threadIdx.x + 256] = en[(size_t)b * C + threadIdx.x + 256];
    __syncthreads();
    float s = fcb[c];
    const float* wp = fcw + (size_t)c * C;
    for (int i = 0; i < C; i += 4) {
        float4 wv = ld4(wp + i);
        s = fmaf(es[i], wv.x, s);
        s = fmaf(es[i + 1], wv.y, s);
        s = fmaf(es[i + 2], wv.z, s);
        s = fmaf(es[i + 3], wv.w, s);
    }
    gam[(size_t)b * C + c] = 1.f / (1.f + __expf(-s));
}

// ---------------- weight prep ----------------
__global__ void prep_small_k(const float* bn1g, const float* bn2g, const float* bn3b,
                             const float* rbnb, const float* lvcbng,
                             const float* enbng, const float* cw,
                             float* s1, float* s2, float* slvc, float* bcat,
                             float* sK, float* c2)
{
    int t = threadIdx.x;
    const float invCB  = rsqrtf(1.f + 1e-6f);
    const float invLVC = rsqrtf(1.f + 1e-5f);
    if (t < 128) { s1[t] = bn1g[t] * invCB; s2[t] = bn2g[t] * invCB; }
    if (t < 512) { slvc[t] = lvcbng[t] * invLVC; bcat[t] = bn3b[t] + rbnb[t]; }
    if (t < 64) {
        sK[t] = enbng[t] * invLVC;
        float s = 0.f;
        for (int c = 0; c < C; ++c) s = fmaf(cw[t * C + c], cw[t * C + c], s);
        c2[t] = s;
    }
}

__global__ void cvt_bf_k(const float* __restrict__ src, u16* __restrict__ dst, int n)
{
    int i = blockIdx.x * 256 + threadIdx.x;
    if (i < n) dst[i] = f2bf(src[i]);
}

__global__ void prep_w2t_k(const float* __restrict__ w2, u16* __restrict__ w2b)
{
    int id = blockIdx.x * 256 + threadIdx.x;   // 128*1152
    int co = id / 1152, k = id % 1152;
    int tap = k >> 7, ci = k & 127;
    w2b[id] = f2bf(w2[co * 1152 + ci * 9 + tap]);
}

__global__ void prep_wcat_k(const float* __restrict__ c3w, const float* __restrict__ rcw,
                            const float* __restrict__ bn3g, const float* __restrict__ rbng,
                            u16* __restrict__ wcatb)
{
    int id = blockIdx.x * 256 + threadIdx.x;   // 512*640
    int co = id / 640, k = id % 640;
    const float invCB = rsqrtf(1.f + 1e-6f);
    float v = (k < 128) ? c3w[co * 128 + k] * (bn3g[co] * invCB)
                        : rcw[co * 512 + (k - 128)] * (rbng[co] * invCB);
    wcatb[id] = f2bf(v);
}

__global__ void prep_cw_k(const float* __restrict__ cw, u16* __restrict__ cwb)
{
    int id = blockIdx.x * 256 + threadIdx.x;   // 128*512
    int r = id >> 9;
    cwb[id] = (r < 64) ? f2bf(cw[id]) : (u16)0;
}

// ---------------------------------------------------------------------------
extern "C" void kernel_launch(void* const* d_in, const int* in_sizes, int n_in,
                              void* d_out, int out_size, void* d_ws, size_t ws_size,
                              hipStream_t stream)
{
    const float* x      = (const float*)d_in[0];
    const float* c1w    = (const float*)d_in[1];
    const float* bn1g   = (const float*)d_in[2];
    const float* bn1b   = (const float*)d_in[3];
    const float* c2w    = (const float*)d_in[4];
    const float* bn2g   = (const float*)d_in[5];
    const float* bn2b   = (const float*)d_in[6];
    const float* c3w    = (const float*)d_in[7];
    const float* bn3g   = (const float*)d_in[8];
    const float* bn3b   = (const float*)d_in[9];
    const float* rcw    = (const float*)d_in[10];
    const float* rbng   = (const float*)d_in[11];
    const float* rbnb   = (const float*)d_in[12];
    const float* lvcw   = (const float*)d_in[13];
    const float* lvcbng = (const float*)d_in[14];
    const float* lvcbnb = (const float*)d_in[15];
    const float* cw     = (const float*)d_in[16];
    const float* scale  = (const float*)d_in[17];
    const float* enbng  = (const float*)d_in[18];
    const float* enbnb  = (const float*)d_in[19];
    const float* fcw    = (const float*)d_in[20];
    const float* fcb    = (const float*)d_in[21];
    float* out = (float*)d_out;
    char* W = (char*)d_ws;

    // ---- workspace layout (bytes) ----
    u16*  xbf  = (u16*)(W + 0);            // 32MB (B,N,512) bf16  [reused as e]
    u16*  e_b  = xbf;
    u16*  h1   = (u16*)(W + 33554432);     // 8MB (B,N,128)        [reused as a]
    u16*  a_b  = h1;
    u16*  h2   = (u16*)(W + 41943040);     // 8MB (B,N,128)        [reused as xc]
    u16*  xc_b = h2;
    float* xb_f = (float*)(W + 50331648);  // 64MB (B,N,512) f32
    u16*  xb_b = (u16*)(W + 117440512);    // 32MB (B,N,512) bf16
    char* wb = W + 150994944;              // weights region
    u16* c1b   = (u16*)(wb);               // 131072 B
    u16* w2b   = (u16*)(wb + 131072);      // 294912 B
    u16* wcatb = (u16*)(wb + 425984);      // 655360 B
    u16* lvcb  = (u16*)(wb + 1081344);     // 524288 B
    u16* cwb   = (u16*)(wb + 1605632);     // 131072 B
    float* fb  = (float*)(wb + 2097152);   // small f32 region
    float* x2v  = fb;                      // 32768
    float* en   = fb + 32768;              // 16384
    float* gam  = fb + 49152;              // 16384
    float* s1   = fb + 65536;              // 128
    float* s2   = s1 + 128;
    float* slvc = s2 + 128;
    float* bcat = slvc + 512;
    float* sK   = bcat + 512;
    float* c2   = sK + 64;                 // 64
    u16* zbuf   = (u16*)(fb + 67584);      // 1KB zeros

    hipMemsetAsync(zbuf, 0, 1024, stream);

    // weight prep
    prep_small_k<<<1, 512, 0, stream>>>(bn1g, bn2g, bn3b, rbnb, lvcbng, enbng, cw,
                                        s1, s2, slvc, bcat, sK, c2);
    cvt_bf_k<<<256, 256, 0, stream>>>(c1w, c1b, 65536);
    cvt_bf_k<<<1024, 256, 0, stream>>>(lvcw, lvcb, 262144);
    prep_w2t_k<<<576, 256, 0, stream>>>(c2w, w2b);
    prep_wcat_k<<<1280, 256, 0, stream>>>(c3w, rcw, bn3g, rbng, wcatb);
    prep_cw_k<<<256, 256, 0, stream>>>(cw, cwb);

    // x (NCHW f32) -> xbf (NHWC bf16)
    tr_in_k<<<dim3(16, 8, 32), 256, 0, stream>>>(x, xbf);

    // conv1 + bn1 + relu -> h1
    gemm_mfma<0, true, false, true><<<dim3(8, 1, 32), 256, 0, stream>>>(
        xbf, nullptr, c1b, nullptr, h1, s1, bn1b, zbuf, 512, 128);
    // conv2 (3x3) + bn2 + relu -> h2
    gemm_mfma<1, true, false, true><<<dim3(8, 1, 32), 256, 0, stream>>>(
        h1, nullptr, w2b, nullptr, h2, s2, bn2b, zbuf, 1152, 128);
    // conv3+bn3 + residual+bn (concat-K, gains folded) + relu -> xb_f, xb_b
    gemm_mfma<2, true, true, true><<<dim3(8, 4, 32), 256, 0, stream>>>(
        h2, xbf, wcatb, xb_f, xb_b, nullptr, bcat, zbuf, 640, 512);
    // lvc + bn + relu -> e
    gemm_mfma<0, true, false, true><<<dim3(8, 4, 32), 256, 0, stream>>>(
        xb_b, nullptr, lvcb, nullptr, e_b, slvc, lvcbnb, zbuf, 512, 512);
    // encoding
    x2_k<<<8192, 256, 0, stream>>>(e_b, x2v);
    gemm_mfma<0, false, false, true><<<dim3(8, 1, 32), 256, 0, stream>>>(
        e_b, nullptr, cwb, nullptr, xc_b, nullptr, nullptr, zbuf, 512, 128);
    softmax_k<<<128, 256, 0, stream>>>(xc_b, x2v, scale, c2, a_b);
    enc_k<<<dim3(4, 32), 256, 0, stream>>>(a_b, e_b, cw, sK, enbnb, en);
    gam_k<<<dim3(32, 2), 256, 0, stream>>>(en, fcw, fcb, gam);
    // final: out(NCHW) = relu(xb*(1+gam))
    final_tr_k<<<dim3(16, 8, 32), 256, 0, stream>>>(xb_f, gam, out);
}

// Round 4
// 397.939 us; speedup vs baseline: 2.8348x; 1.3186x over previous
//
#include <hip/hip_runtime.h>
#include <math.h>

constexpr int BATCH = 32;
constexpr int C     = 512;
constexpr int CM    = 128;
constexpr int KW    = 64;
constexpr int NPIX  = 1024;

typedef unsigned short u16;
typedef __attribute__((ext_vector_type(8))) short bf16x8;
typedef __attribute__((ext_vector_type(4))) float f32x4;
typedef __attribute__((ext_vector_type(8))) unsigned short u16x8;

__device__ __forceinline__ float bf2f(u16 u) {
    unsigned int v = ((unsigned int)u) << 16;
    return __uint_as_float(v);
}
__device__ __forceinline__ u16 f2bf(float f) {
    unsigned int u = __float_as_uint(f);
    u = u + 0x7FFFu + ((u >> 16) & 1u);   // RNE
    return (u16)(u >> 16);
}
__device__ __forceinline__ float4 ld4(const float* p) {
    return *reinterpret_cast<const float4*>(p);
}
__device__ __forceinline__ void gload16(const u16* g, u16* l) {
    __builtin_amdgcn_global_load_lds((const __attribute__((address_space(1))) void*)g,
                                     (__attribute__((address_space(3))) void*)l, 16, 0, 0);
}

// ---------------------------------------------------------------------------
// NHWC bf16 MFMA GEMM, tile TM(n) x 128(co), BK=32.
// MODE 0: A1 is (B,NPIX,K);  MODE 1: 3x3 gather from A1 (B,NPIX,128);
// MODE 2: concat-K: k<128 from A1 (B,NPIX,128), else A2 (B,NPIX,512)
// ---------------------------------------------------------------------------
template<int MODE, int TM, bool RELU>
__global__ __launch_bounds__(256)
void gemm_mfma(const u16* __restrict__ A1, const u16* __restrict__ A2,
               const u16* __restrict__ Wm, u16* __restrict__ outB,
               const float* __restrict__ scale, const float* __restrict__ bias,
               const u16* __restrict__ zbuf, int K, int Cout)
{
    constexpr int MF = TM / 32;           // m-fragments per wave
    __shared__ __align__(16) u16 As[TM * 32];
    __shared__ __align__(16) u16 Bs[4096];
    const int b   = blockIdx.z;
    const int n0  = blockIdx.x * TM;
    const int co0 = blockIdx.y * 128;
    const int t    = threadIdx.x;
    const int lane = t & 63;
    const int w    = t >> 6;
    const int wr = w >> 1, wc = w & 1;
    const int lhi = lane >> 4, llo = lane & 15;

    f32x4 acc[MF][4];
#pragma unroll
    for (int i = 0; i < MF; ++i)
#pragma unroll
        for (int j = 0; j < 4; ++j) acc[i][j] = (f32x4){0.f, 0.f, 0.f, 0.f};

    const int aBase = lhi * TM + wr * (TM / 2) + llo;
    const int bBase = lhi * 128 + wc * 64 + llo;

    for (int k0 = 0; k0 < K; k0 += 32) {
        // ---- A tile: TM rows x 32 k ----
#pragma unroll
        for (int rd = 0; rd < (TM * 4) / 256; ++rd) {
            int ch = t + rd * 256;
            int g  = ch / TM, r = ch % TM;
            int kg = k0 + g * 8;
            const u16* src;
            if (MODE == 0) {
                src = A1 + ((size_t)((b << 10) + n0 + r)) * (size_t)K + kg;
            } else if (MODE == 1) {
                int tap = kg >> 7, ci = kg & 127;
                int n = n0 + r;
                int y = (n >> 5) + tap / 3 - 1;
                int x = (n & 31) + tap % 3 - 1;
                src = ((unsigned)y < 32u && (unsigned)x < 32u)
                    ? A1 + ((size_t)((b << 10) + y * 32 + x)) * 128 + ci
                    : zbuf;
            } else {
                src = (kg < 128)
                    ? A1 + ((size_t)((b << 10) + n0 + r)) * 128 + kg
                    : A2 + ((size_t)((b << 10) + n0 + r)) * 512 + (kg - 128);
            }
            gload16(src, &As[ch * 8]);
        }
        // ---- B tile: 128 co x 32 k ----
#pragma unroll
        for (int rd = 0; rd < 2; ++rd) {
            int ch = t + rd * 256;
            int g = ch >> 7, r = ch & 127;
            gload16(Wm + (size_t)(co0 + r) * (size_t)K + k0 + g * 8, &Bs[ch * 8]);
        }
        __syncthreads();
        const bf16x8* Av = (const bf16x8*)As;
        const bf16x8* Bv = (const bf16x8*)Bs;
        bf16x8 af[MF], bfr[4];
#pragma unroll
        for (int m = 0; m < MF; ++m)  af[m]  = Av[aBase + m * 16];
#pragma unroll
        for (int nf = 0; nf < 4; ++nf) bfr[nf] = Bv[bBase + nf * 16];
#pragma unroll
        for (int m = 0; m < MF; ++m)
#pragma unroll
            for (int nf = 0; nf < 4; ++nf)
                acc[m][nf] = __builtin_amdgcn_mfma_f32_16x16x32_bf16(af[m], bfr[nf], acc[m][nf], 0, 0, 0);
        __syncthreads();
    }
#pragma unroll
    for (int nf = 0; nf < 4; ++nf) {
        int coL = co0 + wc * 64 + nf * 16 + llo;
        float s  = scale ? scale[coL] : 1.f;
        float bi = bias  ? bias[coL]  : 0.f;
#pragma unroll
        for (int m = 0; m < MF; ++m) {
            f32x4 v = acc[m][nf];
#pragma unroll
            for (int q = 0; q < 4; ++q) {
                int row = n0 + wr * (TM / 2) + m * 16 + lhi * 4 + q;
                float val = fmaf(v[q], s, bi);
                if (RELU) val = fmaxf(val, 0.f);
                outB[((size_t)((b << 10) + row)) * (size_t)Cout + coL] = f2bf(val);
            }
        }
    }
}

// ---------------------------------------------------------------------------
// xc GEMM (64n x 64k, K=512) + fused x2, softmax, a_t write, asum atomics
// ---------------------------------------------------------------------------
__global__ __launch_bounds__(256)
void gemm_xc(const u16* __restrict__ e, const u16* __restrict__ cwb,
             const float* __restrict__ scale, const float* __restrict__ c2,
             u16* __restrict__ a_t, float* __restrict__ asum)
{
    const int b  = blockIdx.y;
    const int n0 = blockIdx.x * 64;
    const int t    = threadIdx.x;
    const int lane = t & 63;
    const int w    = t >> 6;
    const int wr = w >> 1, wc = w & 1;
    const int lhi = lane >> 4, llo = lane & 15;

    __shared__ __align__(16) char smem[16640];       // As(4KB)+Bs(4KB) | sm[64][65] f32
    u16* As = (u16*)smem;
    u16* Bs = (u16*)(smem + 4096);
    float (*sm)[65] = (float(*)[65])smem;
    __shared__ float x2s[64], pmax[64][4], psum[64][4], sc_s[64], c2_s[64];
    if (t < 64) { sc_s[t] = scale[t]; c2_s[t] = c2[t]; }

    f32x4 acc[2][2];
#pragma unroll
    for (int i = 0; i < 2; ++i)
#pragma unroll
        for (int j = 0; j < 2; ++j) acc[i][j] = (f32x4){0.f, 0.f, 0.f, 0.f};
    float x2p = 0.f;
    const int aBase = lhi * 64 + wr * 32 + llo;
    const int bBase = lhi * 64 + wc * 32 + llo;
    const int xr = w * 16 + (lane >> 2);   // row this lane accumulates x2 for
    const int xg = lane & 3;

    const int g = t >> 6, r = t & 63;
    for (int k0 = 0; k0 < 512; k0 += 32) {
        gload16(e + ((size_t)((b << 10) + n0 + r)) * 512 + k0 + g * 8, &As[t * 8]);
        gload16(cwb + (size_t)r * 512 + k0 + g * 8, &Bs[t * 8]);
        __syncthreads();
        {   // x2 partial from staged A tile
            u16x8 vv = *(const u16x8*)&As[(xg * 64 + xr) * 8];
#pragma unroll
            for (int j = 0; j < 8; ++j) { float f = bf2f(vv[j]); x2p = fmaf(f, f, x2p); }
        }
        const bf16x8* Av = (const bf16x8*)As;
        const bf16x8* Bv = (const bf16x8*)Bs;
        bf16x8 af[2], bfr[2];
#pragma unroll
        for (int m = 0; m < 2; ++m)  af[m]  = Av[aBase + m * 16];
#pragma unroll
        for (int nf = 0; nf < 2; ++nf) bfr[nf] = Bv[bBase + nf * 16];
#pragma unroll
        for (int m = 0; m < 2; ++m)
#pragma unroll
            for (int nf = 0; nf < 2; ++nf)
                acc[m][nf] = __builtin_amdgcn_mfma_f32_16x16x32_bf16(af[m], bfr[nf], acc[m][nf], 0, 0, 0);
        __syncthreads();
    }
    // x2 reduce over the 4 k-groups (same wave)
    float xs = x2p + __shfl_xor(x2p, 1, 64);
    xs += __shfl_xor(xs, 2, 64);
    if ((lane & 3) == 0) x2s[xr] = xs;
    __syncthreads();
    // sl2 -> sm (LDS reused; staging dead)
#pragma unroll
    for (int m = 0; m < 2; ++m)
#pragma unroll
        for (int nf = 0; nf < 2; ++nf)
#pragma unroll
            for (int q = 0; q < 4; ++q) {
                int rr = wr * 32 + m * 16 + lhi * 4 + q;
                int cc = wc * 32 + nf * 16 + llo;
                sm[rr][cc] = sc_s[cc] * (x2s[rr] - 2.f * acc[m][nf][q] + c2_s[cc]);
            }
    __syncthreads();
    // softmax: 4 threads per row, 16 k each
    const int gq = t >> 6;
    float vloc[16];
    float pm = -1e30f;
#pragma unroll
    for (int j = 0; j < 16; ++j) { float v = sm[r][gq * 16 + j]; vloc[j] = v; pm = fmaxf(pm, v); }
    pmax[r][gq] = pm;
    __syncthreads();
    float mm = fmaxf(fmaxf(pmax[r][0], pmax[r][1]), fmaxf(pmax[r][2], pmax[r][3]));
    float ps = 0.f;
#pragma unroll
    for (int j = 0; j < 16; ++j) { float p = __expf(vloc[j] - mm); vloc[j] = p; ps += p; }
    psum[r][gq] = ps;
    __syncthreads();
    float inv = 1.f / (psum[r][0] + psum[r][1] + psum[r][2] + psum[r][3]);
#pragma unroll
    for (int j = 0; j < 16; ++j) {
        int k = gq * 16 + j;
        float av = vloc[j] * inv;
        a_t[((size_t)((b << 6) + k) << 10) + n0 + r] = f2bf(av);
        sm[r][k] = av;
    }
    __syncthreads();
    // asum: column sums + atomics
    const int kk = t & 63, rg = t >> 6;
    float pa = 0.f;
#pragma unroll
    for (int j = 0; j < 16; ++j) pa += sm[rg * 16 + j][kk];
    atomicAdd(&asum[(b << 6) + kk], pa);
}

// ---------------------------------------------------------------------------
// enc MFMA: out(64k x 64c tile), K=1024 pixels; epilogue asum/BN/relu/mean_k
// ---------------------------------------------------------------------------
__global__ __launch_bounds__(256)
void enc_mfma(const u16* __restrict__ a_t, const u16* __restrict__ e_t,
              const float* __restrict__ cw, const float* __restrict__ asum,
              const float* __restrict__ sK, const float* __restrict__ bK,
              float* __restrict__ en)
{
    const int b  = blockIdx.y;
    const int c0 = blockIdx.x * 64;
    const int t    = threadIdx.x;
    const int lane = t & 63;
    const int w    = t >> 6;
    const int lhi = lane >> 4, llo = lane & 15;
    __shared__ __align__(16) u16 As[2048];
    __shared__ __align__(16) u16 Bs[2048];
    f32x4 acc[4];
#pragma unroll
    for (int i = 0; i < 4; ++i) acc[i] = (f32x4){0.f, 0.f, 0.f, 0.f};
    const int aBase = lhi * 64 + llo;
    const int bBase = lhi * 64 + w * 16 + llo;
    const int g = t >> 6, r = t & 63;

    for (int n0 = 0; n0 < NPIX; n0 += 32) {
        gload16(a_t + ((size_t)((b << 6) + r) << 10) + n0 + g * 8, &As[t * 8]);
        gload16(e_t + ((size_t)((b << 9) + c0 + r) << 10) + n0 + g * 8, &Bs[t * 8]);
        __syncthreads();
        const bf16x8* Av = (const bf16x8*)As;
        const bf16x8* Bv = (const bf16x8*)Bs;
        bf16x8 bfr = Bv[bBase];
#pragma unroll
        for (int m = 0; m < 4; ++m)
            acc[m] = __builtin_amdgcn_mfma_f32_16x16x32_bf16(Av[aBase + m * 16], bfr, acc[m], 0, 0, 0);
        __syncthreads();
    }
    const int c = c0 + w * 16 + llo;
    float s = 0.f;
#pragma unroll
    for (int m = 0; m < 4; ++m)
#pragma unroll
        for (int q = 0; q < 4; ++q) {
            int k = m * 16 + lhi * 4 + q;
            float v = acc[m][q] - asum[(b << 6) + k] * cw[((size_t)k << 9) + c];
            v = fmaxf(fmaf(v, sK[k], bK[k]), 0.f);
            s += v;
        }
    s += __shfl_xor(s, 16, 64);
    s += __shfl_xor(s, 32, 64);
    if (lane < 16) en[(size_t)(b << 9) + c] = s * (1.f / 64.f);
}

// ---------------- NCHW f32 -> NHWC bf16 ----------------
__global__ __launch_bounds__(256)
void tr_in_k(const float* __restrict__ x, u16* __restrict__ xbf)
{
    __shared__ float tile[64][65];
    int b = blockIdx.z, n0 = blockIdx.x * 64, c0 = blockIdx.y * 64, t = threadIdx.x;
#pragma unroll
    for (int q = 0; q < 16; ++q) {
        int idx = t + 256 * q;
        int c = idx >> 6, n = idx & 63;
        tile[c][n] = x[((size_t)((b << 9) + c0 + c) << 10) + n0 + n];
    }
    __syncthreads();
#pragma unroll
    for (int q = 0; q < 16; ++q) {
        int idx = t + 256 * q;
        int nn = idx >> 6, cc = idx & 63;
        xbf[((size_t)((b << 10) + n0 + nn) << 9) + c0 + cc] = f2bf(tile[cc][nn]);
    }
}

// ---------------- e NHWC bf16 -> e_t NCHW bf16 ----------------
__global__ __launch_bounds__(256)
void e_tr_k(const u16* __restrict__ e, u16* __restrict__ e_t)
{
    __shared__ u16 tile[64][65];
    int b = blockIdx.z, n0 = blockIdx.x * 64, c0 = blockIdx.y * 64, t = threadIdx.x;
#pragma unroll
    for (int q = 0; q < 16; ++q) {
        int idx = t + 256 * q;
        int n = idx >> 6, c = idx & 63;
        tile[n][c] = e[((size_t)((b << 10) + n0 + n) << 9) + c0 + c];
    }
    __syncthreads();
#pragma unroll
    for (int q = 0; q < 16; ++q) {
        int idx = t + 256 * q;
        int cc = idx >> 6, nn = idx & 63;
        e_t[((size_t)((b << 9) + c0 + cc) << 10) + n0 + nn] = tile[nn][cc];
    }
}

// ---------------- final: out(NCHW f32) = relu(xb_bf16*(1+gam)) ----------------
__global__ __launch_bounds__(256)
void final_tr_k(const u16* __restrict__ xb, const float* __restrict__ gam,
                float* __restrict__ out)
{
    __shared__ float tile[64][65];
    int b = blockIdx.z, n0 = blockIdx.x * 64, c0 = blockIdx.y * 64, t = threadIdx.x;
#pragma unroll
    for (int q = 0; q < 16; ++q) {
        int idx = t + 256 * q;
        int n = idx >> 6, c = idx & 63;
        float gm = 1.f + gam[(b << 9) + c0 + c];
        float v = bf2f(xb[((size_t)((b << 10) + n0 + n) << 9) + c0 + c]) * gm;
        tile[n][c] = fmaxf(v, 0.f);
    }
    __syncthreads();
#pragma unroll
    for (int q = 0; q < 16; ++q) {
        int idx = t + 256 * q;
        int cc = idx >> 6, nn = idx & 63;
        out[((size_t)((b << 9) + c0 + cc) << 10) + n0 + nn] = tile[nn][cc];
    }
}

// ---------------- SE gate ----------------
__global__ __launch_bounds__(256)
void gam_k(const float* __restrict__ en, const float* __restrict__ fcw,
           const float* __restrict__ fcb, float* __restrict__ gam)
{
    int b = blockIdx.x;
    int c = blockIdx.y * 256 + threadIdx.x;
    __shared__ float es[C];
    es[threadIdx.x]       = en[(size_t)b * C + threadIdx.x];
    es[threadIdx.x + 256] = en[(size_t)b * C + threadIdx.x + 256];
    __syncthreads();
    float s = fcb[c];
    const float* wp = fcw + (size_t)c * C;
    for (int i = 0; i < C; i += 4) {
        float4 wv = ld4(wp + i);
        s = fmaf(es[i], wv.x, s);
        s = fmaf(es[i + 1], wv.y, s);
        s = fmaf(es[i + 2], wv.z, s);
        s = fmaf(es[i + 3], wv.w, s);
    }
    gam[(size_t)b * C + c] = 1.f / (1.f + __expf(-s));
}

// ---------------- merged weight prep ----------------
__global__ __launch_bounds__(256)
void prep_all_k(const float* c1w, const float* bn1g, const float* bn2g,
                const float* c2w, const float* c3w, const float* bn3g,
                const float* bn3b, const float* rcw, const float* rbng,
                const float* rbnb, const float* lvcw, const float* lvcbng,
                const float* enbng, const float* cw,
                u16* c1b, u16* w2b, u16* wcatb, u16* lvcb, u16* cwb,
                float* s1, float* s2, float* slvc, float* bcat,
                float* sK, float* c2, float* asum, u16* zbuf)
{
    const float invCB  = rsqrtf(1.f + 1e-6f);
    const float invLVC = rsqrtf(1.f + 1e-5f);
    long id = (long)blockIdx.x * 256 + threadIdx.x;
    if (id < 327680) {                       // wcatb (512co x 640k)
        int co = (int)(id / 640), k = (int)(id % 640);
        float v = (k < 128) ? c3w[co * 128 + k] * (bn3g[co] * invCB)
                            : rcw[co * 512 + (k - 128)] * (rbng[co] * invCB);
        wcatb[id] = f2bf(v);
        return;
    }
    id -= 327680;
    if (id < 147456) {                       // w2b (128co x 1152k)
        int co = (int)(id / 1152), k = (int)(id % 1152);
        int tap = k >> 7, ci = k & 127;
        w2b[id] = f2bf(c2w[co * 1152 + ci * 9 + tap]);
        return;
    }
    id -= 147456;
    if (id < 262144) { lvcb[id] = f2bf(lvcw[id]); return; }
    id -= 262144;
    if (id < 65536)  { c1b[id]  = f2bf(c1w[id]);  return; }
    id -= 65536;
    if (id < 32768)  { cwb[id]  = f2bf(cw[id]);   return; }
    id -= 32768;
    if (id < 2048)   { asum[id] = 0.f; return; }
    id -= 2048;
    if (id < 1024)   { zbuf[id] = 0;   return; }
    id -= 1024;
    if (id < 128) { s1[id] = bn1g[id] * invCB; return; }
    id -= 128;
    if (id < 128) { s2[id] = bn2g[id] * invCB; return; }
    id -= 128;
    if (id < 512) { slvc[id] = lvcbng[id] * invLVC; return; }
    id -= 512;
    if (id < 512) { bcat[id] = bn3b[id] + rbnb[id]; return; }
    id -= 512;
    if (id < 64)  { sK[id] = enbng[id] * invLVC; return; }
    id -= 64;
    if (id < 64) {
        float s = 0.f;
        for (int c = 0; c < C; ++c) s = fmaf(cw[id * C + c], cw[id * C + c], s);
        c2[id] = s;
    }
}

// ---------------------------------------------------------------------------
extern "C" void kernel_launch(void* const* d_in, const int* in_sizes, int n_in,
                              void* d_out, int out_size, void* d_ws, size_t ws_size,
                              hipStream_t stream)
{
    const float* x      = (const float*)d_in[0];
    const float* c1w    = (const float*)d_in[1];
    const float* bn1g   = (const float*)d_in[2];
    const float* bn1b   = (const float*)d_in[3];
    const float* c2w    = (const float*)d_in[4];
    const float* bn2g   = (const float*)d_in[5];
    const float* bn2b   = (const float*)d_in[6];
    const float* c3w    = (const float*)d_in[7];
    const float* bn3g   = (const float*)d_in[8];
    const float* bn3b   = (const float*)d_in[9];
    const float* rcw    = (const float*)d_in[10];
    const float* rbng   = (const float*)d_in[11];
    const float* rbnb   = (const float*)d_in[12];
    const float* lvcw   = (const float*)d_in[13];
    const float* lvcbng = (const float*)d_in[14];
    const float* lvcbnb = (const float*)d_in[15];
    const float* cw     = (const float*)d_in[16];
    const float* scale  = (const float*)d_in[17];
    const float* enbng  = (const float*)d_in[18];
    const float* enbnb  = (const float*)d_in[19];
    const float* fcw    = (const float*)d_in[20];
    const float* fcb    = (const float*)d_in[21];
    float* out = (float*)d_out;
    char* W = (char*)d_ws;

    // ---- workspace layout (bytes) ----
    u16*  xbf  = (u16*)(W);                 // 32MB (B,N,512) x in NHWC  [later: e]
    u16*  e_b  = xbf;
    u16*  h1   = (u16*)(W + 33554432);      // 8MB (B,N,128)   [later: a_t (4MB)]
    u16*  a_t  = h1;
    u16*  h2   = (u16*)(W + 41943040);      // 8MB (B,N,128)
    u16*  xb_b = (u16*)(W + 50331648);      // 32MB (B,N,512) bf16
    u16*  e_t  = (u16*)(W + 83886080);      // 32MB (B,512,N) bf16
    char* wb   = W + 117440512;             // weights region
    u16* c1b   = (u16*)(wb);                // 131072 B
    u16* w2b   = (u16*)(wb + 131072);       // 294912 B
    u16* wcatb = (u16*)(wb + 425984);       // 655360 B
    u16* lvcb  = (u16*)(wb + 1081344);      // 524288 B
    u16* cwb   = (u16*)(wb + 1605632);      // 65536 B
    float* fb  = (float*)(wb + 1671168);
    float* asum = fb;                       // 2048
    float* en   = fb + 2048;                // 16384
    float* gam  = fb + 18432;               // 16384
    float* s1   = fb + 34816;               // 128
    float* s2   = s1 + 128;
    float* slvc = s2 + 128;
    float* bcat = slvc + 512;
    float* sK   = bcat + 512;
    float* c2   = sK + 64;
    u16* zbuf   = (u16*)(c2 + 64);          // 2KB

    // prep (single launch): 840,064 work items
    prep_all_k<<<3282, 256, 0, stream>>>(c1w, bn1g, bn2g, c2w, c3w, bn3g, bn3b,
                                         rcw, rbng, rbnb, lvcw, lvcbng, enbng, cw,
                                         c1b, w2b, wcatb, lvcb, cwb,
                                         s1, s2, slvc, bcat, sK, c2, asum, zbuf);

    // x (NCHW f32) -> xbf (NHWC bf16)
    tr_in_k<<<dim3(16, 8, 32), 256, 0, stream>>>(x, xbf);

    // conv1 + bn1 + relu -> h1  (64n tiles, grid 512)
    gemm_mfma<0, 64, true><<<dim3(16, 1, 32), 256, 0, stream>>>(
        xbf, nullptr, c1b, h1, s1, bn1b, zbuf, 512, 128);
    // conv2 (3x3) + bn2 + relu -> h2
    gemm_mfma<1, 64, true><<<dim3(16, 1, 32), 256, 0, stream>>>(
        h1, nullptr, w2b, h2, s2, bn2b, zbuf, 1152, 128);
    // conv3+bn3 + residual+bn (concat-K) + relu -> xb_b
    gemm_mfma<2, 128, true><<<dim3(8, 4, 32), 256, 0, stream>>>(
        h2, xbf, wcatb, xb_b, nullptr, bcat, zbuf, 640, 512);
    // lvc + bn + relu -> e
    gemm_mfma<0, 128, true><<<dim3(8, 4, 32), 256, 0, stream>>>(
        xb_b, nullptr, lvcb, e_b, slvc, lvcbnb, zbuf, 512, 512);
    // e -> e_t (NCHW bf16)
    e_tr_k<<<dim3(16, 8, 32), 256, 0, stream>>>(e_b, e_t);
    // xc GEMM + x2 + softmax + a_t + asum
    gemm_xc<<<dim3(16, 32), 256, 0, stream>>>(e_b, cwb, scale, c2, a_t, asum);
    // enc (MFMA) + BN + relu + mean_k -> en
    enc_mfma<<<dim3(8, 32), 256, 0, stream>>>(a_t, e_t, cw, asum, sK, enbnb, en);
    // SE gate
    gam_k<<<dim3(32, 2), 256, 0, stream>>>(en, fcw, fcb, gam);
    // final: out(NCHW f32) = relu(xb*(1+gam))
    final_tr_k<<<dim3(16, 8, 32), 256, 0, stream>>>(xb_b, gam, out);
}

// Round 5
// 385.218 us; speedup vs baseline: 2.9284x; 1.0330x over previous
//
#include <hip/hip_runtime.h>
#include <math.h>

constexpr int BATCH = 32;
constexpr int C     = 512;
constexpr int CM    = 128;
constexpr int KW    = 64;
constexpr int NPIX  = 1024;

typedef unsigned short u16;
typedef __attribute__((ext_vector_type(8))) short bf16x8;
typedef __attribute__((ext_vector_type(4))) float f32x4;
typedef __attribute__((ext_vector_type(4))) unsigned short u16x4;
typedef __attribute__((ext_vector_type(8))) unsigned short u16x8;

__device__ __forceinline__ float bf2f(u16 u) {
    unsigned int v = ((unsigned int)u) << 16;
    return __uint_as_float(v);
}
__device__ __forceinline__ u16 f2bf(float f) {
    unsigned int u = __float_as_uint(f);
    u = u + 0x7FFFu + ((u >> 16) & 1u);   // RNE
    return (u16)(u >> 16);
}
__device__ __forceinline__ float4 ld4(const float* p) {
    return *reinterpret_cast<const float4*>(p);
}
__device__ __forceinline__ void gload16(const u16* g, u16* l) {
    __builtin_amdgcn_global_load_lds((const __attribute__((address_space(1))) void*)g,
                                     (__attribute__((address_space(3))) void*)l, 16, 0, 0);
}

// ---------------------------------------------------------------------------
// NHWC bf16 MFMA GEMM, tile TM(n) x 128(co), BK=32, 2-phase double-buffered:
//   STAGE(next) issued before compute(cur); ONE __syncthreads per K-step
//   (its vmcnt(0) drain overlaps the MFMA phase).
// MODE 0: A1 is (B,NPIX,K);  MODE 1: 3x3 gather from A1 (B,NPIX,128);
// MODE 2: concat-K: k<128 from A1 (B,NPIX,128), else A2 (B,NPIX,512)
// WTR: additionally write transposed (B,Cout,NPIX) bf16 output (u16x4 stores)
// ---------------------------------------------------------------------------
template<int MODE, int TM, bool RELU, bool WTR>
__global__ __launch_bounds__(256)
void gemm_mfma(const u16* __restrict__ A1, const u16* __restrict__ A2,
               const u16* __restrict__ Wm, u16* __restrict__ outB,
               u16* __restrict__ outT,
               const float* __restrict__ scale, const float* __restrict__ bias,
               const u16* __restrict__ zbuf, int K, int Cout)
{
    constexpr int MF = TM / 32;           // m-fragments per wave
    __shared__ __align__(16) u16 As[2][TM * 32];
    __shared__ __align__(16) u16 Bs[2][4096];
    const int b   = blockIdx.z;
    const int n0  = blockIdx.x * TM;
    const int co0 = blockIdx.y * 128;
    const int t    = threadIdx.x;
    const int lane = t & 63;
    const int w    = t >> 6;
    const int wr = w >> 1, wc = w & 1;
    const int lhi = lane >> 4, llo = lane & 15;

    f32x4 acc[MF][4];
#pragma unroll
    for (int i = 0; i < MF; ++i)
#pragma unroll
        for (int j = 0; j < 4; ++j) acc[i][j] = (f32x4){0.f, 0.f, 0.f, 0.f};

    const int aBase = lhi * TM + wr * (TM / 2) + llo;
    const int bBase = lhi * 128 + wc * 64 + llo;
    const int nt = K / 32;

    auto stage = [&](int buf, int k0) {
#pragma unroll
        for (int rd = 0; rd < (TM * 4) / 256; ++rd) {
            int ch = t + rd * 256;
            int g  = ch / TM, r = ch % TM;
            int kg = k0 + g * 8;
            const u16* src;
            if (MODE == 0) {
                src = A1 + ((size_t)((b << 10) + n0 + r)) * (size_t)K + kg;
            } else if (MODE == 1) {
                int tap = kg >> 7, ci = kg & 127;
                int n = n0 + r;
                int y = (n >> 5) + tap / 3 - 1;
                int x = (n & 31) + tap % 3 - 1;
                src = ((unsigned)y < 32u && (unsigned)x < 32u)
                    ? A1 + ((size_t)((b << 10) + y * 32 + x)) * 128 + ci
                    : zbuf;
            } else {
                src = (kg < 128)
                    ? A1 + ((size_t)((b << 10) + n0 + r)) * 128 + kg
                    : A2 + ((size_t)((b << 10) + n0 + r)) * 512 + (kg - 128);
            }
            gload16(src, &As[buf][ch * 8]);
        }
#pragma unroll
        for (int rd = 0; rd < 2; ++rd) {
            int ch = t + rd * 256;
            int g = ch >> 7, r = ch & 127;
            gload16(Wm + (size_t)(co0 + r) * (size_t)K + k0 + g * 8, &Bs[buf][ch * 8]);
        }
    };

    stage(0, 0);
    __syncthreads();                       // vmcnt(0): buf0 ready
    int cur = 0;
    for (int ti = 0; ti < nt; ++ti) {
        if (ti + 1 < nt) stage(cur ^ 1, (ti + 1) * 32);   // async into other buf
        const bf16x8* Av = (const bf16x8*)As[cur];
        const bf16x8* Bv = (const bf16x8*)Bs[cur];
        bf16x8 af[MF], bfr[4];
#pragma unroll
        for (int m = 0; m < MF; ++m)  af[m]  = Av[aBase + m * 16];
#pragma unroll
        for (int nf = 0; nf < 4; ++nf) bfr[nf] = Bv[bBase + nf * 16];
#pragma unroll
        for (int m = 0; m < MF; ++m)
#pragma unroll
            for (int nf = 0; nf < 4; ++nf)
                acc[m][nf] = __builtin_amdgcn_mfma_f32_16x16x32_bf16(af[m], bfr[nf], acc[m][nf], 0, 0, 0);
        __syncthreads();                   // drains next-tile loads too
        cur ^= 1;
    }
#pragma unroll
    for (int nf = 0; nf < 4; ++nf) {
        int coL = co0 + wc * 64 + nf * 16 + llo;
        float s  = scale ? scale[coL] : 1.f;
        float bi = bias  ? bias[coL]  : 0.f;
#pragma unroll
        for (int m = 0; m < MF; ++m) {
            f32x4 v = acc[m][nf];
            int rowb = n0 + wr * (TM / 2) + m * 16 + lhi * 4;
            u16 o[4];
#pragma unroll
            for (int q = 0; q < 4; ++q) {
                float val = fmaf(v[q], s, bi);
                if (RELU) val = fmaxf(val, 0.f);
                o[q] = f2bf(val);
                outB[((size_t)((b << 10) + rowb + q)) * (size_t)Cout + coL] = o[q];
            }
            if (WTR) {
                u16x4 ov;
                ov[0] = o[0]; ov[1] = o[1]; ov[2] = o[2]; ov[3] = o[3];
                *(u16x4*)(outT + (((size_t)(b * Cout + coL)) << 10) + rowb) = ov;
            }
        }
    }
}

// ---------------------------------------------------------------------------
// xc GEMM (64n x 64k, K=512) + fused x2, softmax, a_t write, asum atomics
// ---------------------------------------------------------------------------
__global__ __launch_bounds__(256)
void gemm_xc(const u16* __restrict__ e, const u16* __restrict__ cwb,
             const float* __restrict__ scale, const float* __restrict__ c2,
             u16* __restrict__ a_t, float* __restrict__ asum)
{
    const int b  = blockIdx.y;
    const int n0 = blockIdx.x * 64;
    const int t    = threadIdx.x;
    const int lane = t & 63;
    const int w    = t >> 6;
    const int wr = w >> 1, wc = w & 1;
    const int lhi = lane >> 4, llo = lane & 15;

    __shared__ __align__(16) char smem[16640];       // As(4KB)+Bs(4KB) | sm[64][65] f32
    u16* As = (u16*)smem;
    u16* Bs = (u16*)(smem + 4096);
    float (*sm)[65] = (float(*)[65])smem;
    __shared__ float x2s[64], pmax[64][4], psum[64][4], sc_s[64], c2_s[64];
    if (t < 64) { sc_s[t] = scale[t]; c2_s[t] = c2[t]; }

    f32x4 acc[2][2];
#pragma unroll
    for (int i = 0; i < 2; ++i)
#pragma unroll
        for (int j = 0; j < 2; ++j) acc[i][j] = (f32x4){0.f, 0.f, 0.f, 0.f};
    float x2p = 0.f;
    const int aBase = lhi * 64 + wr * 32 + llo;
    const int bBase = lhi * 64 + wc * 32 + llo;
    const int xr = w * 16 + (lane >> 2);   // row this lane accumulates x2 for
    const int xg = lane & 3;

    const int g = t >> 6, r = t & 63;
    for (int k0 = 0; k0 < 512; k0 += 32) {
        gload16(e + ((size_t)((b << 10) + n0 + r)) * 512 + k0 + g * 8, &As[t * 8]);
        gload16(cwb + (size_t)r * 512 + k0 + g * 8, &Bs[t * 8]);
        __syncthreads();
        {   // x2 partial from staged A tile
            u16x8 vv = *(const u16x8*)&As[(xg * 64 + xr) * 8];
#pragma unroll
            for (int j = 0; j < 8; ++j) { float f = bf2f(vv[j]); x2p = fmaf(f, f, x2p); }
        }
        const bf16x8* Av = (const bf16x8*)As;
        const bf16x8* Bv = (const bf16x8*)Bs;
        bf16x8 af[2], bfr[2];
#pragma unroll
        for (int m = 0; m < 2; ++m)  af[m]  = Av[aBase + m * 16];
#pragma unroll
        for (int nf = 0; nf < 2; ++nf) bfr[nf] = Bv[bBase + nf * 16];
#pragma unroll
        for (int m = 0; m < 2; ++m)
#pragma unroll
            for (int nf = 0; nf < 2; ++nf)
                acc[m][nf] = __builtin_amdgcn_mfma_f32_16x16x32_bf16(af[m], bfr[nf], acc[m][nf], 0, 0, 0);
        __syncthreads();
    }
    // x2 reduce over the 4 k-groups (same wave)
    float xs = x2p + __shfl_xor(x2p, 1, 64);
    xs += __shfl_xor(xs, 2, 64);
    if ((lane & 3) == 0) x2s[xr] = xs;
    __syncthreads();
    // sl2 -> sm (LDS reused; staging dead)
#pragma unroll
    for (int m = 0; m < 2; ++m)
#pragma unroll
        for (int nf = 0; nf < 2; ++nf)
#pragma unroll
            for (int q = 0; q < 4; ++q) {
                int rr = wr * 32 + m * 16 + lhi * 4 + q;
                int cc = wc * 32 + nf * 16 + llo;
                sm[rr][cc] = sc_s[cc] * (x2s[rr] - 2.f * acc[m][nf][q] + c2_s[cc]);
            }
    __syncthreads();
    // softmax: 4 threads per row, 16 k each
    const int gq = t >> 6;
    float vloc[16];
    float pm = -1e30f;
#pragma unroll
    for (int j = 0; j < 16; ++j) { float v = sm[r][gq * 16 + j]; vloc[j] = v; pm = fmaxf(pm, v); }
    pmax[r][gq] = pm;
    __syncthreads();
    float mm = fmaxf(fmaxf(pmax[r][0], pmax[r][1]), fmaxf(pmax[r][2], pmax[r][3]));
    float ps = 0.f;
#pragma unroll
    for (int j = 0; j < 16; ++j) { float p = __expf(vloc[j] - mm); vloc[j] = p; ps += p; }
    psum[r][gq] = ps;
    __syncthreads();
    float inv = 1.f / (psum[r][0] + psum[r][1] + psum[r][2] + psum[r][3]);
#pragma unroll
    for (int j = 0; j < 16; ++j) {
        int k = gq * 16 + j;
        float av = vloc[j] * inv;
        a_t[((size_t)((b << 6) + k) << 10) + n0 + r] = f2bf(av);
        sm[r][k] = av;
    }
    __syncthreads();
    // asum: column sums + atomics
    const int kk = t & 63, rg = t >> 6;
    float pa = 0.f;
#pragma unroll
    for (int j = 0; j < 16; ++j) pa += sm[rg * 16 + j][kk];
    atomicAdd(&asum[(b << 6) + kk], pa);
}

// ---------------------------------------------------------------------------
// enc MFMA: out(64k x 64c tile), K=1024 pixels; epilogue asum/BN/relu/mean_k
// ---------------------------------------------------------------------------
__global__ __launch_bounds__(256)
void enc_mfma(const u16* __restrict__ a_t, const u16* __restrict__ e_t,
              const float* __restrict__ cw, const float* __restrict__ asum,
              const float* __restrict__ sK, const float* __restrict__ bK,
              float* __restrict__ en)
{
    const int b  = blockIdx.y;
    const int c0 = blockIdx.x * 64;
    const int t    = threadIdx.x;
    const int lane = t & 63;
    const int w    = t >> 6;
    const int lhi = lane >> 4, llo = lane & 15;
    __shared__ __align__(16) u16 As[2048];
    __shared__ __align__(16) u16 Bs[2048];
    f32x4 acc[4];
#pragma unroll
    for (int i = 0; i < 4; ++i) acc[i] = (f32x4){0.f, 0.f, 0.f, 0.f};
    const int aBase = lhi * 64 + llo;
    const int bBase = lhi * 64 + w * 16 + llo;
    const int g = t >> 6, r = t & 63;

    for (int n0 = 0; n0 < NPIX; n0 += 32) {
        gload16(a_t + ((size_t)((b << 6) + r) << 10) + n0 + g * 8, &As[t * 8]);
        gload16(e_t + ((size_t)((b << 9) + c0 + r) << 10) + n0 + g * 8, &Bs[t * 8]);
        __syncthreads();
        const bf16x8* Av = (const bf16x8*)As;
        const bf16x8* Bv = (const bf16x8*)Bs;
        bf16x8 bfr = Bv[bBase];
#pragma unroll
        for (int m = 0; m < 4; ++m)
            acc[m] = __builtin_amdgcn_mfma_f32_16x16x32_bf16(Av[aBase + m * 16], bfr, acc[m], 0, 0, 0);
        __syncthreads();
    }
    const int c = c0 + w * 16 + llo;
    float s = 0.f;
#pragma unroll
    for (int m = 0; m < 4; ++m)
#pragma unroll
        for (int q = 0; q < 4; ++q) {
            int k = m * 16 + lhi * 4 + q;
            float v = acc[m][q] - asum[(b << 6) + k] * cw[((size_t)k << 9) + c];
            v = fmaxf(fmaf(v, sK[k], bK[k]), 0.f);
            s += v;
        }
    s += __shfl_xor(s, 16, 64);
    s += __shfl_xor(s, 32, 64);
    if (lane < 16) en[(size_t)(b << 9) + c] = s * (1.f / 64.f);
}

// ---------------- NCHW f32 -> NHWC bf16 ----------------
__global__ __launch_bounds__(256)
void tr_in_k(const float* __restrict__ x, u16* __restrict__ xbf)
{
    __shared__ float tile[64][65];
    int b = blockIdx.z, n0 = blockIdx.x * 64, c0 = blockIdx.y * 64, t = threadIdx.x;
#pragma unroll
    for (int q = 0; q < 16; ++q) {
        int idx = t + 256 * q;
        int c = idx >> 6, n = idx & 63;
        tile[c][n] = x[((size_t)((b << 9) + c0 + c) << 10) + n0 + n];
    }
    __syncthreads();
#pragma unroll
    for (int q = 0; q < 16; ++q) {
        int idx = t + 256 * q;
        int nn = idx >> 6, cc = idx & 63;
        xbf[((size_t)((b << 10) + n0 + nn) << 9) + c0 + cc] = f2bf(tile[cc][nn]);
    }
}

// ---------------- final: out(NCHW f32) = relu(xb_bf16*(1+gam)) ----------------
__global__ __launch_bounds__(256)
void final_tr_k(const u16* __restrict__ xb, const float* __restrict__ gam,
                float* __restrict__ out)
{
    __shared__ float tile[64][65];
    int b = blockIdx.z, n0 = blockIdx.x * 64, c0 = blockIdx.y * 64, t = threadIdx.x;
#pragma unroll
    for (int q = 0; q < 16; ++q) {
        int idx = t + 256 * q;
        int n = idx >> 6, c = idx & 63;
        float gm = 1.f + gam[(b << 9) + c0 + c];
        float v = bf2f(xb[((size_t)((b << 10) + n0 + n) << 9) + c0 + c]) * gm;
        tile[n][c] = fmaxf(v, 0.f);
    }
    __syncthreads();
#pragma unroll
    for (int q = 0; q < 16; ++q) {
        int idx = t + 256 * q;
        int cc = idx >> 6, nn = idx & 63;
        out[((size_t)((b << 9) + c0 + cc) << 10) + n0 + nn] = tile[nn][cc];
    }
}

// ---------------- SE gate ----------------
__global__ __launch_bounds__(256)
void gam_k(const float* __restrict__ en, const float* __restrict__ fcw,
           const float* __restrict__ fcb, float* __restrict__ gam)
{
    int b = blockIdx.x;
    int c = blockIdx.y * 256 + threadIdx.x;
    __shared__ float es[C];
    es[threadIdx.x]       = en[(size_t)b * C + threadIdx.x];
    es[threadIdx.x + 256] = en[(size_t)b * C + threadIdx.x + 256];
    __syncthreads();
    float s = fcb[c];
    const float* wp = fcw + (size_t)c * C;
    for (int i = 0; i < C; i += 4) {
        float4 wv = ld4(wp + i);
        s = fmaf(es[i], wv.x, s);
        s = fmaf(es[i + 1], wv.y, s);
        s = fmaf(es[i + 2], wv.z, s);
        s = fmaf(es[i + 3], wv.w, s);
    }
    gam[(size_t)b * C + c] = 1.f / (1.f + __expf(-s));
}

// ---------------- merged weight prep ----------------
__global__ __launch_bounds__(256)
void prep_all_k(const float* c1w, const float* bn1g, const float* bn2g,
                const float* c2w, const float* c3w, const float* bn3g,
                const float* bn3b, const float* rcw, const float* rbng,
                const float* rbnb, const float* lvcw, const float* lvcbng,
                const float* enbng, const float* cw,
                u16* c1b, u16* w2b, u16* wcatb, u16* lvcb, u16* cwb,
                float* s1, float* s2, float* slvc, float* bcat,
                float* sK, float* c2, float* asum, u16* zbuf)
{
    const float invCB  = rsqrtf(1.f + 1e-6f);
    const float invLVC = rsqrtf(1.f + 1e-5f);
    long id = (long)blockIdx.x * 256 + threadIdx.x;
    if (id < 327680) {                       // wcatb (512co x 640k)
        int co = (int)(id / 640), k = (int)(id % 640);
        float v = (k < 128) ? c3w[co * 128 + k] * (bn3g[co] * invCB)
                            : rcw[co * 512 + (k - 128)] * (rbng[co] * invCB);
        wcatb[id] = f2bf(v);
        return;
    }
    id -= 327680;
    if (id < 147456) {                       // w2b (128co x 1152k)
        int co = (int)(id / 1152), k = (int)(id % 1152);
        int tap = k >> 7, ci = k & 127;
        w2b[id] = f2bf(c2w[co * 1152 + ci * 9 + tap]);
        return;
    }
    id -= 147456;
    if (id < 262144) { lvcb[id] = f2bf(lvcw[id]); return; }
    id -= 262144;
    if (id < 65536)  { c1b[id]  = f2bf(c1w[id]);  return; }
    id -= 65536;
    if (id < 32768)  { cwb[id]  = f2bf(cw[id]);   return; }
    id -= 32768;
    if (id < 2048)   { asum[id] = 0.f; return; }
    id -= 2048;
    if (id < 1024)   { zbuf[id] = 0;   return; }
    id -= 1024;
    if (id < 128) { s1[id] = bn1g[id] * invCB; return; }
    id -= 128;
    if (id < 128) { s2[id] = bn2g[id] * invCB; return; }
    id -= 128;
    if (id < 512) { slvc[id] = lvcbng[id] * invLVC; return; }
    id -= 512;
    if (id < 512) { bcat[id] = bn3b[id] + rbnb[id]; return; }
    id -= 512;
    if (id < 64)  { sK[id] = enbng[id] * invLVC; return; }
    id -= 64;
    if (id < 64) {
        float s = 0.f;
        for (int c = 0; c < C; ++c) s = fmaf(cw[id * C + c], cw[id * C + c], s);
        c2[id] = s;
    }
}

// ---------------------------------------------------------------------------
extern "C" void kernel_launch(void* const* d_in, const int* in_sizes, int n_in,
                              void* d_out, int out_size, void* d_ws, size_t ws_size,
                              hipStream_t stream)
{
    const float* x      = (const float*)d_in[0];
    const float* c1w    = (const float*)d_in[1];
    const float* bn1g   = (const float*)d_in[2];
    const float* bn1b   = (const float*)d_in[3];
    const float* c2w    = (const float*)d_in[4];
    const float* bn2g   = (const float*)d_in[5];
    const float* bn2b   = (const float*)d_in[6];
    const float* c3w    = (const float*)d_in[7];
    const float* bn3g   = (const float*)d_in[8];
    const float* bn3b   = (const float*)d_in[9];
    const float* rcw    = (const float*)d_in[10];
    const float* rbng   = (const float*)d_in[11];
    const float* rbnb   = (const float*)d_in[12];
    const float* lvcw   = (const float*)d_in[13];
    const float* lvcbng = (const float*)d_in[14];
    const float* lvcbnb = (const float*)d_in[15];
    const float* cw     = (const float*)d_in[16];
    const float* scale  = (const float*)d_in[17];
    const float* enbng  = (const float*)d_in[18];
    const float* enbnb  = (const float*)d_in[19];
    const float* fcw    = (const float*)d_in[20];
    const float* fcb    = (const float*)d_in[21];
    float* out = (float*)d_out;
    char* W = (char*)d_ws;

    // ---- workspace layout (bytes) ----
    u16*  xbf  = (u16*)(W);                 // 32MB (B,N,512) x in NHWC  [later: e]
    u16*  e_b  = xbf;
    u16*  h1   = (u16*)(W + 33554432);      // 8MB (B,N,128)   [later: a_t (4MB)]
    u16*  a_t  = h1;
    u16*  h2   = (u16*)(W + 41943040);      // 8MB (B,N,128)
    u16*  xb_b = (u16*)(W + 50331648);      // 32MB (B,N,512) bf16
    u16*  e_t  = (u16*)(W + 83886080);      // 32MB (B,512,N) bf16
    char* wb   = W + 117440512;             // weights region
    u16* c1b   = (u16*)(wb);                // 131072 B
    u16* w2b   = (u16*)(wb + 131072);       // 294912 B
    u16* wcatb = (u16*)(wb + 425984);       // 655360 B
    u16* lvcb  = (u16*)(wb + 1081344);      // 524288 B
    u16* cwb   = (u16*)(wb + 1605632);      // 65536 B
    float* fb  = (float*)(wb + 1671168);
    float* asum = fb;                       // 2048
    float* en   = fb + 2048;                // 16384
    float* gam  = fb + 18432;               // 16384
    float* s1   = fb + 34816;               // 128
    float* s2   = s1 + 128;
    float* slvc = s2 + 128;
    float* bcat = slvc + 512;
    float* sK   = bcat + 512;
    float* c2   = sK + 64;
    u16* zbuf   = (u16*)(c2 + 64);          // 2KB

    // prep (single launch)
    prep_all_k<<<3282, 256, 0, stream>>>(c1w, bn1g, bn2g, c2w, c3w, bn3g, bn3b,
                                         rcw, rbng, rbnb, lvcw, lvcbng, enbng, cw,
                                         c1b, w2b, wcatb, lvcb, cwb,
                                         s1, s2, slvc, bcat, sK, c2, asum, zbuf);

    // x (NCHW f32) -> xbf (NHWC bf16)
    tr_in_k<<<dim3(16, 8, 32), 256, 0, stream>>>(x, xbf);

    // conv1 + bn1 + relu -> h1
    gemm_mfma<0, 64, true, false><<<dim3(16, 1, 32), 256, 0, stream>>>(
        xbf, nullptr, c1b, h1, nullptr, s1, bn1b, zbuf, 512, 128);
    // conv2 (3x3) + bn2 + relu -> h2
    gemm_mfma<1, 64, true, false><<<dim3(16, 1, 32), 256, 0, stream>>>(
        h1, nullptr, w2b, h2, nullptr, s2, bn2b, zbuf, 1152, 128);
    // conv3+bn3 + residual+bn (concat-K) + relu -> xb_b
    gemm_mfma<2, 128, true, false><<<dim3(8, 4, 32), 256, 0, stream>>>(
        h2, xbf, wcatb, xb_b, nullptr, nullptr, bcat, zbuf, 640, 512);
    // lvc + bn + relu -> e (NHWC) AND e_t (NCHW) via dual-write epilogue
    gemm_mfma<0, 128, true, true><<<dim3(8, 4, 32), 256, 0, stream>>>(
        xb_b, nullptr, lvcb, e_b, e_t, slvc, lvcbnb, zbuf, 512, 512);
    // xc GEMM + x2 + softmax + a_t + asum
    gemm_xc<<<dim3(16, 32), 256, 0, stream>>>(e_b, cwb, scale, c2, a_t, asum);
    // enc (MFMA) + BN + relu + mean_k -> en
    enc_mfma<<<dim3(8, 32), 256, 0, stream>>>(a_t, e_t, cw, asum, sK, enbnb, en);
    // SE gate
    gam_k<<<dim3(32, 2), 256, 0, stream>>>(en, fcw, fcb, gam);
    // final: out(NCHW f32) = relu(xb*(1+gam))
    final_tr_k<<<dim3(16, 8, 32), 256, 0, stream>>>(xb_b, gam, out);
}

// Round 6
// 384.384 us; speedup vs baseline: 2.9348x; 1.0022x over previous
//
#include <hip/hip_runtime.h>
#include <math.h>

constexpr int BATCH = 32;
constexpr int C     = 512;
constexpr int CM    = 128;
constexpr int KW    = 64;
constexpr int NPIX  = 1024;

typedef unsigned short u16;
typedef __attribute__((ext_vector_type(8))) short bf16x8;
typedef __attribute__((ext_vector_type(4))) float f32x4;
typedef __attribute__((ext_vector_type(4))) unsigned short u16x4;
typedef __attribute__((ext_vector_type(8))) unsigned short u16x8;

__device__ __forceinline__ float bf2f(u16 u) {
    unsigned int v = ((unsigned int)u) << 16;
    return __uint_as_float(v);
}
__device__ __forceinline__ u16 f2bf(float f) {
    unsigned int u = __float_as_uint(f);
    u = u + 0x7FFFu + ((u >> 16) & 1u);   // RNE
    return (u16)(u >> 16);
}
__device__ __forceinline__ float4 ld4(const float* p) {
    return *reinterpret_cast<const float4*>(p);
}
__device__ __forceinline__ void gload16(const u16* g, u16* l) {
    __builtin_amdgcn_global_load_lds((const __attribute__((address_space(1))) void*)g,
                                     (__attribute__((address_space(3))) void*)l, 16, 0, 0);
}

// ---------------------------------------------------------------------------
// NHWC bf16 MFMA GEMM, tile TM(n) x 128(co), BK=64 single-buffer 2-barrier.
// Per K-step: stage (TM+128)x64 tile, barrier, 2x(k-slice frag reads + 16 MFMA),
// barrier. BK=64 halves barrier count vs BK=32 and doubles compute per stall.
// MODE 0: A1 is (B,NPIX,K);  MODE 1: 3x3 gather from A1 (B,NPIX,128);
// MODE 2: concat-K: k<128 from A1 (B,NPIX,128), else A2 (B,NPIX,512)
// WTR: additionally write transposed (B,Cout,NPIX) bf16 output (u16x4 stores)
// ---------------------------------------------------------------------------
template<int MODE, int TM, bool RELU, bool WTR>
__global__ __launch_bounds__(256)
void gemm_mfma(const u16* __restrict__ A1, const u16* __restrict__ A2,
               const u16* __restrict__ Wm, u16* __restrict__ outB,
               u16* __restrict__ outT,
               const float* __restrict__ scale, const float* __restrict__ bias,
               const u16* __restrict__ zbuf, int K, int Cout)
{
    constexpr int MF = TM / 32;           // m-fragments per wave
    __shared__ __align__(16) u16 As[TM * 64];     // chunk (g,r) at (g*TM+r)*8
    __shared__ __align__(16) u16 Bs[128 * 64];    // chunk (g,r) at (g*128+r)*8
    const int b   = blockIdx.z;
    const int n0  = blockIdx.x * TM;
    const int co0 = blockIdx.y * 128;
    const int t    = threadIdx.x;
    const int lane = t & 63;
    const int w    = t >> 6;
    const int wr = w >> 1, wc = w & 1;
    const int lhi = lane >> 4, llo = lane & 15;

    f32x4 acc[MF][4];
#pragma unroll
    for (int i = 0; i < MF; ++i)
#pragma unroll
        for (int j = 0; j < 4; ++j) acc[i][j] = (f32x4){0.f, 0.f, 0.f, 0.f};

    for (int k0 = 0; k0 < K; k0 += 64) {
        // ---- A tile: TM rows x 64 k = TM*8 chunks ----
#pragma unroll
        for (int rd = 0; rd < (TM * 8) / 256; ++rd) {
            int ch = t + rd * 256;
            int g  = ch / TM, r = ch % TM;
            int kg = k0 + g * 8;
            const u16* src;
            if (MODE == 0) {
                src = A1 + ((size_t)((b << 10) + n0 + r)) * (size_t)K + kg;
            } else if (MODE == 1) {
                int tap = kg >> 7, ci = kg & 127;
                int n = n0 + r;
                int y = (n >> 5) + tap / 3 - 1;
                int x = (n & 31) + tap % 3 - 1;
                src = ((unsigned)y < 32u && (unsigned)x < 32u)
                    ? A1 + ((size_t)((b << 10) + y * 32 + x)) * 128 + ci
                    : zbuf;
            } else {
                src = (kg < 128)
                    ? A1 + ((size_t)((b << 10) + n0 + r)) * 128 + kg
                    : A2 + ((size_t)((b << 10) + n0 + r)) * 512 + (kg - 128);
            }
            gload16(src, &As[ch * 8]);
        }
        // ---- B tile: 128 co x 64 k = 1024 chunks ----
#pragma unroll
        for (int rd = 0; rd < 4; ++rd) {
            int ch = t + rd * 256;
            int g = ch >> 7, r = ch & 127;
            gload16(Wm + (size_t)(co0 + r) * (size_t)K + k0 + g * 8, &Bs[ch * 8]);
        }
        __syncthreads();
        const bf16x8* Av = (const bf16x8*)As;
        const bf16x8* Bv = (const bf16x8*)Bs;
#pragma unroll
        for (int kk = 0; kk < 2; ++kk) {       // two k=32 slices of the 64-k tile
            bf16x8 af[MF], bfr[4];
#pragma unroll
            for (int m = 0; m < MF; ++m)
                af[m] = Av[(kk * 4 + lhi) * TM + wr * (TM / 2) + m * 16 + llo];
#pragma unroll
            for (int nf = 0; nf < 4; ++nf)
                bfr[nf] = Bv[(kk * 4 + lhi) * 128 + wc * 64 + nf * 16 + llo];
#pragma unroll
            for (int m = 0; m < MF; ++m)
#pragma unroll
                for (int nf = 0; nf < 4; ++nf)
                    acc[m][nf] = __builtin_amdgcn_mfma_f32_16x16x32_bf16(af[m], bfr[nf], acc[m][nf], 0, 0, 0);
        }
        __syncthreads();
    }
#pragma unroll
    for (int nf = 0; nf < 4; ++nf) {
        int coL = co0 + wc * 64 + nf * 16 + llo;
        float s  = scale ? scale[coL] : 1.f;
        float bi = bias  ? bias[coL]  : 0.f;
#pragma unroll
        for (int m = 0; m < MF; ++m) {
            f32x4 v = acc[m][nf];
            int rowb = n0 + wr * (TM / 2) + m * 16 + lhi * 4;
            u16 o[4];
#pragma unroll
            for (int q = 0; q < 4; ++q) {
                float val = fmaf(v[q], s, bi);
                if (RELU) val = fmaxf(val, 0.f);
                o[q] = f2bf(val);
                outB[((size_t)((b << 10) + rowb + q)) * (size_t)Cout + coL] = o[q];
            }
            if (WTR) {
                u16x4 ov;
                ov[0] = o[0]; ov[1] = o[1]; ov[2] = o[2]; ov[3] = o[3];
                *(u16x4*)(outT + (((size_t)(b * Cout + coL)) << 10) + rowb) = ov;
            }
        }
    }
}

// ---------------------------------------------------------------------------
// xc GEMM (64n x 64k, K=512) + fused x2, softmax, a_t write, asum atomics
// ---------------------------------------------------------------------------
__global__ __launch_bounds__(256)
void gemm_xc(const u16* __restrict__ e, const u16* __restrict__ cwb,
             const float* __restrict__ scale, const float* __restrict__ c2,
             u16* __restrict__ a_t, float* __restrict__ asum)
{
    const int b  = blockIdx.y;
    const int n0 = blockIdx.x * 64;
    const int t    = threadIdx.x;
    const int lane = t & 63;
    const int w    = t >> 6;
    const int wr = w >> 1, wc = w & 1;
    const int lhi = lane >> 4, llo = lane & 15;

    __shared__ __align__(16) char smem[16640];       // As(4KB)+Bs(4KB) | sm[64][65] f32
    u16* As = (u16*)smem;
    u16* Bs = (u16*)(smem + 4096);
    float (*sm)[65] = (float(*)[65])smem;
    __shared__ float x2s[64], pmax[64][4], psum[64][4], sc_s[64], c2_s[64];
    if (t < 64) { sc_s[t] = scale[t]; c2_s[t] = c2[t]; }

    f32x4 acc[2][2];
#pragma unroll
    for (int i = 0; i < 2; ++i)
#pragma unroll
        for (int j = 0; j < 2; ++j) acc[i][j] = (f32x4){0.f, 0.f, 0.f, 0.f};
    float x2p = 0.f;
    const int aBase = lhi * 64 + wr * 32 + llo;
    const int bBase = lhi * 64 + wc * 32 + llo;
    const int xr = w * 16 + (lane >> 2);   // row this lane accumulates x2 for
    const int xg = lane & 3;

    const int g = t >> 6, r = t & 63;
    for (int k0 = 0; k0 < 512; k0 += 32) {
        gload16(e + ((size_t)((b << 10) + n0 + r)) * 512 + k0 + g * 8, &As[t * 8]);
        gload16(cwb + (size_t)r * 512 + k0 + g * 8, &Bs[t * 8]);
        __syncthreads();
        {   // x2 partial from staged A tile
            u16x8 vv = *(const u16x8*)&As[(xg * 64 + xr) * 8];
#pragma unroll
            for (int j = 0; j < 8; ++j) { float f = bf2f(vv[j]); x2p = fmaf(f, f, x2p); }
        }
        const bf16x8* Av = (const bf16x8*)As;
        const bf16x8* Bv = (const bf16x8*)Bs;
        bf16x8 af[2], bfr[2];
#pragma unroll
        for (int m = 0; m < 2; ++m)  af[m]  = Av[aBase + m * 16];
#pragma unroll
        for (int nf = 0; nf < 2; ++nf) bfr[nf] = Bv[bBase + nf * 16];
#pragma unroll
        for (int m = 0; m < 2; ++m)
#pragma unroll
            for (int nf = 0; nf < 2; ++nf)
                acc[m][nf] = __builtin_amdgcn_mfma_f32_16x16x32_bf16(af[m], bfr[nf], acc[m][nf], 0, 0, 0);
        __syncthreads();
    }
    // x2 reduce over the 4 k-groups (same wave)
    float xs = x2p + __shfl_xor(x2p, 1, 64);
    xs += __shfl_xor(xs, 2, 64);
    if ((lane & 3) == 0) x2s[xr] = xs;
    __syncthreads();
    // sl2 -> sm (LDS reused; staging dead)
#pragma unroll
    for (int m = 0; m < 2; ++m)
#pragma unroll
        for (int nf = 0; nf < 2; ++nf)
#pragma unroll
            for (int q = 0; q < 4; ++q) {
                int rr = wr * 32 + m * 16 + lhi * 4 + q;
                int cc = wc * 32 + nf * 16 + llo;
                sm[rr][cc] = sc_s[cc] * (x2s[rr] - 2.f * acc[m][nf][q] + c2_s[cc]);
            }
    __syncthreads();
    // softmax: 4 threads per row, 16 k each
    const int gq = t >> 6;
    float vloc[16];
    float pm = -1e30f;
#pragma unroll
    for (int j = 0; j < 16; ++j) { float v = sm[r][gq * 16 + j]; vloc[j] = v; pm = fmaxf(pm, v); }
    pmax[r][gq] = pm;
    __syncthreads();
    float mm = fmaxf(fmaxf(pmax[r][0], pmax[r][1]), fmaxf(pmax[r][2], pmax[r][3]));
    float ps = 0.f;
#pragma unroll
    for (int j = 0; j < 16; ++j) { float p = __expf(vloc[j] - mm); vloc[j] = p; ps += p; }
    psum[r][gq] = ps;
    __syncthreads();
    float inv = 1.f / (psum[r][0] + psum[r][1] + psum[r][2] + psum[r][3]);
#pragma unroll
    for (int j = 0; j < 16; ++j) {
        int k = gq * 16 + j;
        float av = vloc[j] * inv;
        a_t[((size_t)((b << 6) + k) << 10) + n0 + r] = f2bf(av);
        sm[r][k] = av;
    }
    __syncthreads();
    // asum: column sums + atomics
    const int kk = t & 63, rg = t >> 6;
    float pa = 0.f;
#pragma unroll
    for (int j = 0; j < 16; ++j) pa += sm[rg * 16 + j][kk];
    atomicAdd(&asum[(b << 6) + kk], pa);
}

// ---------------------------------------------------------------------------
// enc MFMA: out(64k x 64c tile), K=1024 pixels; epilogue asum/BN/relu/mean_k
// ---------------------------------------------------------------------------
__global__ __launch_bounds__(256)
void enc_mfma(const u16* __restrict__ a_t, const u16* __restrict__ e_t,
              const float* __restrict__ cw, const float* __restrict__ asum,
              const float* __restrict__ sK, const float* __restrict__ bK,
              float* __restrict__ en)
{
    const int b  = blockIdx.y;
    const int c0 = blockIdx.x * 64;
    const int t    = threadIdx.x;
    const int lane = t & 63;
    const int w    = t >> 6;
    const int lhi = lane >> 4, llo = lane & 15;
    __shared__ __align__(16) u16 As[2048];
    __shared__ __align__(16) u16 Bs[2048];
    f32x4 acc[4];
#pragma unroll
    for (int i = 0; i < 4; ++i) acc[i] = (f32x4){0.f, 0.f, 0.f, 0.f};
    const int aBase = lhi * 64 + llo;
    const int bBase = lhi * 64 + w * 16 + llo;
    const int g = t >> 6, r = t & 63;

    for (int n0 = 0; n0 < NPIX; n0 += 32) {
        gload16(a_t + ((size_t)((b << 6) + r) << 10) + n0 + g * 8, &As[t * 8]);
        gload16(e_t + ((size_t)((b << 9) + c0 + r) << 10) + n0 + g * 8, &Bs[t * 8]);
        __syncthreads();
        const bf16x8* Av = (const bf16x8*)As;
        const bf16x8* Bv = (const bf16x8*)Bs;
        bf16x8 bfr = Bv[bBase];
#pragma unroll
        for (int m = 0; m < 4; ++m)
            acc[m] = __builtin_amdgcn_mfma_f32_16x16x32_bf16(Av[aBase + m * 16], bfr, acc[m], 0, 0, 0);
        __syncthreads();
    }
    const int c = c0 + w * 16 + llo;
    float s = 0.f;
#pragma unroll
    for (int m = 0; m < 4; ++m)
#pragma unroll
        for (int q = 0; q < 4; ++q) {
            int k = m * 16 + lhi * 4 + q;
            float v = acc[m][q] - asum[(b << 6) + k] * cw[((size_t)k << 9) + c];
            v = fmaxf(fmaf(v, sK[k], bK[k]), 0.f);
            s += v;
        }
    s += __shfl_xor(s, 16, 64);
    s += __shfl_xor(s, 32, 64);
    if (lane < 16) en[(size_t)(b << 9) + c] = s * (1.f / 64.f);
}

// ---------------- NCHW f32 -> NHWC bf16 ----------------
__global__ __launch_bounds__(256)
void tr_in_k(const float* __restrict__ x, u16* __restrict__ xbf)
{
    __shared__ float tile[64][65];
    int b = blockIdx.z, n0 = blockIdx.x * 64, c0 = blockIdx.y * 64, t = threadIdx.x;
#pragma unroll
    for (int q = 0; q < 16; ++q) {
        int idx = t + 256 * q;
        int c = idx >> 6, n = idx & 63;
        tile[c][n] = x[((size_t)((b << 9) + c0 + c) << 10) + n0 + n];
    }
    __syncthreads();
#pragma unroll
    for (int q = 0; q < 16; ++q) {
        int idx = t + 256 * q;
        int nn = idx >> 6, cc = idx & 63;
        xbf[((size_t)((b << 10) + n0 + nn) << 9) + c0 + cc] = f2bf(tile[cc][nn]);
    }
}

// ---------------- final: out(NCHW f32) = relu(xb_bf16*(1+gam)) ----------------
__global__ __launch_bounds__(256)
void final_tr_k(const u16* __restrict__ xb, const float* __restrict__ gam,
                float* __restrict__ out)
{
    __shared__ float tile[64][65];
    int b = blockIdx.z, n0 = blockIdx.x * 64, c0 = blockIdx.y * 64, t = threadIdx.x;
#pragma unroll
    for (int q = 0; q < 16; ++q) {
        int idx = t + 256 * q;
        int n = idx >> 6, c = idx & 63;
        float gm = 1.f + gam[(b << 9) + c0 + c];
        float v = bf2f(xb[((size_t)((b << 10) + n0 + n) << 9) + c0 + c]) * gm;
        tile[n][c] = fmaxf(v, 0.f);
    }
    __syncthreads();
#pragma unroll
    for (int q = 0; q < 16; ++q) {
        int idx = t + 256 * q;
        int cc = idx >> 6, nn = idx & 63;
        out[((size_t)((b << 9) + c0 + cc) << 10) + n0 + nn] = tile[nn][cc];
    }
}

// ---------------- SE gate ----------------
__global__ __launch_bounds__(256)
void gam_k(const float* __restrict__ en, const float* __restrict__ fcw,
           const float* __restrict__ fcb, float* __restrict__ gam)
{
    int b = blockIdx.x;
    int c = blockIdx.y * 256 + threadIdx.x;
    __shared__ float es[C];
    es[threadIdx.x]       = en[(size_t)b * C + threadIdx.x];
    es[threadIdx.x + 256] = en[(size_t)b * C + threadIdx.x + 256];
    __syncthreads();
    float s = fcb[c];
    const float* wp = fcw + (size_t)c * C;
    for (int i = 0; i < C; i += 4) {
        float4 wv = ld4(wp + i);
        s = fmaf(es[i], wv.x, s);
        s = fmaf(es[i + 1], wv.y, s);
        s = fmaf(es[i + 2], wv.z, s);
        s = fmaf(es[i + 3], wv.w, s);
    }
    gam[(size_t)b * C + c] = 1.f / (1.f + __expf(-s));
}

// ---------------- merged weight prep ----------------
__global__ __launch_bounds__(256)
void prep_all_k(const float* c1w, const float* bn1g, const float* bn2g,
                const float* c2w, const float* c3w, const float* bn3g,
                const float* bn3b, const float* rcw, const float* rbng,
                const float* rbnb, const float* lvcw, const float* lvcbng,
                const float* enbng, const float* cw,
                u16* c1b, u16* w2b, u16* wcatb, u16* lvcb, u16* cwb,
                float* s1, float* s2, float* slvc, float* bcat,
                float* sK, float* c2, float* asum, u16* zbuf)
{
    const float invCB  = rsqrtf(1.f + 1e-6f);
    const float invLVC = rsqrtf(1.f + 1e-5f);
    long id = (long)blockIdx.x * 256 + threadIdx.x;
    if (id < 327680) {                       // wcatb (512co x 640k)
        int co = (int)(id / 640), k = (int)(id % 640);
        float v = (k < 128) ? c3w[co * 128 + k] * (bn3g[co] * invCB)
                            : rcw[co * 512 + (k - 128)] * (rbng[co] * invCB);
        wcatb[id] = f2bf(v);
        return;
    }
    id -= 327680;
    if (id < 147456) {                       // w2b (128co x 1152k)
        int co = (int)(id / 1152), k = (int)(id % 1152);
        int tap = k >> 7, ci = k & 127;
        w2b[id] = f2bf(c2w[co * 1152 + ci * 9 + tap]);
        return;
    }
    id -= 147456;
    if (id < 262144) { lvcb[id] = f2bf(lvcw[id]); return; }
    id -= 262144;
    if (id < 65536)  { c1b[id]  = f2bf(c1w[id]);  return; }
    id -= 65536;
    if (id < 32768)  { cwb[id]  = f2bf(cw[id]);   return; }
    id -= 32768;
    if (id < 2048)   { asum[id] = 0.f; return; }
    id -= 2048;
    if (id < 1024)   { zbuf[id] = 0;   return; }
    id -= 1024;
    if (id < 128) { s1[id] = bn1g[id] * invCB; return; }
    id -= 128;
    if (id < 128) { s2[id] = bn2g[id] * invCB; return; }
    id -= 128;
    if (id < 512) { slvc[id] = lvcbng[id] * invLVC; return; }
    id -= 512;
    if (id < 512) { bcat[id] = bn3b[id] + rbnb[id]; return; }
    id -= 512;
    if (id < 64)  { sK[id] = enbng[id] * invLVC; return; }
    id -= 64;
    if (id < 64) {
        float s = 0.f;
        for (int c = 0; c < C; ++c) s = fmaf(cw[id * C + c], cw[id * C + c], s);
        c2[id] = s;
    }
}

// ---------------------------------------------------------------------------
extern "C" void kernel_launch(void* const* d_in, const int* in_sizes, int n_in,
                              void* d_out, int out_size, void* d_ws, size_t ws_size,
                              hipStream_t stream)
{
    const float* x      = (const float*)d_in[0];
    const float* c1w    = (const float*)d_in[1];
    const float* bn1g   = (const float*)d_in[2];
    const float* bn1b   = (const float*)d_in[3];
    const float* c2w    = (const float*)d_in[4];
    const float* bn2g   = (const float*)d_in[5];
    const float* bn2b   = (const float*)d_in[6];
    const float* c3w    = (const float*)d_in[7];
    const float* bn3g   = (const float*)d_in[8];
    const float* bn3b   = (const float*)d_in[9];
    const float* rcw    = (const float*)d_in[10];
    const float* rbng   = (const float*)d_in[11];
    const float* rbnb   = (const float*)d_in[12];
    const float* lvcw   = (const float*)d_in[13];
    const float* lvcbng = (const float*)d_in[14];
    const float* lvcbnb = (const float*)d_in[15];
    const float* cw     = (const float*)d_in[16];
    const float* scale  = (const float*)d_in[17];
    const float* enbng  = (const float*)d_in[18];
    const float* enbnb  = (const float*)d_in[19];
    const float* fcw    = (const float*)d_in[20];
    const float* fcb    = (const float*)d_in[21];
    float* out = (float*)d_out;
    char* W = (char*)d_ws;

    // ---- workspace layout (bytes) ----
    u16*  xbf  = (u16*)(W);                 // 32MB (B,N,512) x in NHWC  [later: e]
    u16*  e_b  = xbf;
    u16*  h1   = (u16*)(W + 33554432);      // 8MB (B,N,128)   [later: a_t (4MB)]
    u16*  a_t  = h1;
    u16*  h2   = (u16*)(W + 41943040);      // 8MB (B,N,128)
    u16*  xb_b = (u16*)(W + 50331648);      // 32MB (B,N,512) bf16
    u16*  e_t  = (u16*)(W + 83886080);      // 32MB (B,512,N) bf16
    char* wb   = W + 117440512;             // weights region
    u16* c1b   = (u16*)(wb);                // 131072 B
    u16* w2b   = (u16*)(wb + 131072);       // 294912 B
    u16* wcatb = (u16*)(wb + 425984);       // 655360 B
    u16* lvcb  = (u16*)(wb + 1081344);      // 524288 B
    u16* cwb   = (u16*)(wb + 1605632);      // 65536 B
    float* fb  = (float*)(wb + 1671168);
    float* asum = fb;                       // 2048
    float* en   = fb + 2048;                // 16384
    float* gam  = fb + 18432;               // 16384
    float* s1   = fb + 34816;               // 128
    float* s2   = s1 + 128;
    float* slvc = s2 + 128;
    float* bcat = slvc + 512;
    float* sK   = bcat + 512;
    float* c2   = sK + 64;
    u16* zbuf   = (u16*)(c2 + 64);          // 2KB

    // prep (single launch)
    prep_all_k<<<3282, 256, 0, stream>>>(c1w, bn1g, bn2g, c2w, c3w, bn3g, bn3b,
                                         rcw, rbng, rbnb, lvcw, lvcbng, enbng, cw,
                                         c1b, w2b, wcatb, lvcb, cwb,
                                         s1, s2, slvc, bcat, sK, c2, asum, zbuf);

    // x (NCHW f32) -> xbf (NHWC bf16)
    tr_in_k<<<dim3(16, 8, 32), 256, 0, stream>>>(x, xbf);

    // conv1 + bn1 + relu -> h1
    gemm_mfma<0, 64, true, false><<<dim3(16, 1, 32), 256, 0, stream>>>(
        xbf, nullptr, c1b, h1, nullptr, s1, bn1b, zbuf, 512, 128);
    // conv2 (3x3) + bn2 + relu -> h2
    gemm_mfma<1, 64, true, false><<<dim3(16, 1, 32), 256, 0, stream>>>(
        h1, nullptr, w2b, h2, nullptr, s2, bn2b, zbuf, 1152, 128);
    // conv3+bn3 + residual+bn (concat-K) + relu -> xb_b
    gemm_mfma<2, 128, true, false><<<dim3(8, 4, 32), 256, 0, stream>>>(
        h2, xbf, wcatb, xb_b, nullptr, nullptr, bcat, zbuf, 640, 512);
    // lvc + bn + relu -> e (NHWC) AND e_t (NCHW) via dual-write epilogue
    gemm_mfma<0, 128, true, true><<<dim3(8, 4, 32), 256, 0, stream>>>(
        xb_b, nullptr, lvcb, e_b, e_t, slvc, lvcbnb, zbuf, 512, 512);
    // xc GEMM + x2 + softmax + a_t + asum
    gemm_xc<<<dim3(16, 32), 256, 0, stream>>>(e_b, cwb, scale, c2, a_t, asum);
    // enc (MFMA) + BN + relu + mean_k -> en
    enc_mfma<<<dim3(8, 32), 256, 0, stream>>>(a_t, e_t, cw, asum, sK, enbnb, en);
    // SE gate
    gam_k<<<dim3(32, 2), 256, 0, stream>>>(en, fcw, fcb, gam);
    // final: out(NCHW f32) = relu(xb*(1+gam))
    final_tr_k<<<dim3(16, 8, 32), 256, 0, stream>>>(xb_b, gam, out);
}

// Round 11
// 377.492 us; speedup vs baseline: 2.9884x; 1.0183x over previous
//
#include <hip/hip_runtime.h>
#include <math.h>

constexpr int BATCH = 32;
constexpr int C     = 512;
constexpr int CM    = 128;
constexpr int KW    = 64;
constexpr int NPIX  = 1024;

typedef unsigned short u16;
typedef __attribute__((ext_vector_type(8))) short bf16x8;
typedef __attribute__((ext_vector_type(4))) float f32x4;
typedef __attribute__((ext_vector_type(4))) unsigned short u16x4;
typedef __attribute__((ext_vector_type(8))) unsigned short u16x8;

__device__ __forceinline__ float bf2f(u16 u) {
    unsigned int v = ((unsigned int)u) << 16;
    return __uint_as_float(v);
}
__device__ __forceinline__ u16 f2bf(float f) {
    unsigned int u = __float_as_uint(f);
    u = u + 0x7FFFu + ((u >> 16) & 1u);   // RNE
    return (u16)(u >> 16);
}
__device__ __forceinline__ float4 ld4(const float* p) {
    return *reinterpret_cast<const float4*>(p);
}
__device__ __forceinline__ void gload16(const u16* g, u16* l) {
    __builtin_amdgcn_global_load_lds((const __attribute__((address_space(1))) void*)g,
                                     (__attribute__((address_space(3))) void*)l, 16, 0, 0);
}

// ---------------------------------------------------------------------------
// NHWC bf16 MFMA GEMM, tile TM(n) x 128(co), BK=64, depth-2 ping-pong pipeline
// with COUNTED vmcnt (T4): per tile {vmcnt(LPS); barrier; compute(buf);
// barrier; restage(buf)}, so the other buffer's LPS loads stay in flight
// across barriers and their HBM latency hides under compute.
// Requires K/64 even (all call sites: 8/18/10/8).
// MODE 0: A1 is (B,NPIX,K);  MODE 1: 3x3 gather from A1 (B,NPIX,128);
// MODE 2: concat-K: k<128 from A1 (B,NPIX,128), else A2 (B,NPIX,512)
// WTR: additionally write transposed (B,Cout,NPIX) bf16 output (u16x4 stores)
// ---------------------------------------------------------------------------
template<int MODE, int TM, bool RELU, bool WTR>
__global__ __launch_bounds__(256)
void gemm_mfma(const u16* __restrict__ A1, const u16* __restrict__ A2,
               const u16* __restrict__ Wm, u16* __restrict__ outB,
               u16* __restrict__ outT,
               const float* __restrict__ scale, const float* __restrict__ bias,
               const u16* __restrict__ zbuf, int K, int Cout)
{
    constexpr int MF  = TM / 32;            // m-fragments per wave
    constexpr int ALD = (TM * 8) / 256;     // A gload16 per thread per stage
    constexpr int LPS = ALD + 4;            // total gload16 per thread per stage
    __shared__ __align__(16) u16 As[2][TM * 64];    // chunk (g,r) at (g*TM+r)*8
    __shared__ __align__(16) u16 Bs[2][128 * 64];   // chunk (g,r) at (g*128+r)*8
    const int b   = blockIdx.z;
    const int n0  = blockIdx.x * TM;
    const int co0 = blockIdx.y * 128;
    const int t    = threadIdx.x;
    const int lane = t & 63;
    const int w    = t >> 6;
    const int wr = w >> 1, wc = w & 1;
    const int lhi = lane >> 4, llo = lane & 15;

    f32x4 acc[MF][4];
#pragma unroll
    for (int i = 0; i < MF; ++i)
#pragma unroll
        for (int j = 0; j < 4; ++j) acc[i][j] = (f32x4){0.f, 0.f, 0.f, 0.f};

    auto stage = [&](u16* Ad, u16* Bd, int k0) {
#pragma unroll
        for (int rd = 0; rd < ALD; ++rd) {
            int ch = t + rd * 256;
            int g  = ch / TM, r = ch % TM;
            int kg = k0 + g * 8;
            const u16* src;
            if (MODE == 0) {
                src = A1 + ((size_t)((b << 10) + n0 + r)) * (size_t)K + kg;
            } else if (MODE == 1) {
                int tap = kg >> 7, ci = kg & 127;
                int n = n0 + r;
                int y = (n >> 5) + tap / 3 - 1;
                int x = (n & 31) + tap % 3 - 1;
                src = ((unsigned)y < 32u && (unsigned)x < 32u)
                    ? A1 + ((size_t)((b << 10) + y * 32 + x)) * 128 + ci
                    : zbuf;
            } else {
                src = (kg < 128)
                    ? A1 + ((size_t)((b << 10) + n0 + r)) * 128 + kg
                    : A2 + ((size_t)((b << 10) + n0 + r)) * 512 + (kg - 128);
            }
            gload16(src, Ad + ch * 8);
        }
#pragma unroll
        for (int rd = 0; rd < 4; ++rd) {
            int ch = t + rd * 256;
            int g = ch >> 7, r = ch & 127;
            gload16(Wm + (size_t)(co0 + r) * (size_t)K + k0 + g * 8, Bd + ch * 8);
        }
    };

    auto compute = [&](const u16* Ad, const u16* Bd) {
        const bf16x8* Av = (const bf16x8*)Ad;
        const bf16x8* Bv = (const bf16x8*)Bd;
#pragma unroll
        for (int kk = 0; kk < 2; ++kk) {       // two k=32 slices of the 64-k tile
            bf16x8 af[MF], bfr[4];
#pragma unroll
            for (int m = 0; m < MF; ++m)
                af[m] = Av[(kk * 4 + lhi) * TM + wr * (TM / 2) + m * 16 + llo];
#pragma unroll
            for (int nf = 0; nf < 4; ++nf)
                bfr[nf] = Bv[(kk * 4 + lhi) * 128 + wc * 64 + nf * 16 + llo];
#pragma unroll
            for (int m = 0; m < MF; ++m)
#pragma unroll
                for (int nf = 0; nf < 4; ++nf)
                    acc[m][nf] = __builtin_amdgcn_mfma_f32_16x16x32_bf16(af[m], bfr[nf], acc[m][nf], 0, 0, 0);
        }
    };

    const int nt = K >> 6;                    // K/64, even at all call sites
    stage(As[0], Bs[0], 0);
    stage(As[1], Bs[1], 64);

    for (int ti = 0; ti < nt; ti += 2) {
        // ---- buf0: tile ti ----
        // wait: buf0's loads retired (buf1's LPS may remain in flight)
        asm volatile("s_waitcnt vmcnt(%0)" :: "n"(LPS) : "memory");
        __builtin_amdgcn_s_barrier();
        __builtin_amdgcn_sched_barrier(0);
        compute(As[0], Bs[0]);
        __builtin_amdgcn_sched_barrier(0);
        __builtin_amdgcn_s_barrier();          // all waves done reading buf0
        if (ti + 2 < nt) {
            stage(As[0], Bs[0], (ti + 2) << 6);
            asm volatile("s_waitcnt vmcnt(%0)" :: "n"(LPS) : "memory");  // buf1 ready
        } else {
            asm volatile("s_waitcnt vmcnt(0)" ::: "memory");             // drain: buf1 ready
        }
        // ---- buf1: tile ti+1 ----
        __builtin_amdgcn_s_barrier();
        __builtin_amdgcn_sched_barrier(0);
        compute(As[1], Bs[1]);
        __builtin_amdgcn_sched_barrier(0);
        __builtin_amdgcn_s_barrier();          // all waves done reading buf1
        if (ti + 3 < nt) stage(As[1], Bs[1], (ti + 3) << 6);
    }

#pragma unroll
    for (int nf = 0; nf < 4; ++nf) {
        int coL = co0 + wc * 64 + nf * 16 + llo;
        float s  = scale ? scale[coL] : 1.f;
        float bi = bias  ? bias[coL]  : 0.f;
#pragma unroll
        for (int m = 0; m < MF; ++m) {
            f32x4 v = acc[m][nf];
            int rowb = n0 + wr * (TM / 2) + m * 16 + lhi * 4;
            u16 o[4];
#pragma unroll
            for (int q = 0; q < 4; ++q) {
                float val = fmaf(v[q], s, bi);
                if (RELU) val = fmaxf(val, 0.f);
                o[q] = f2bf(val);
                outB[((size_t)((b << 10) + rowb + q)) * (size_t)Cout + coL] = o[q];
            }
            if (WTR) {
                u16x4 ov;
                ov[0] = o[0]; ov[1] = o[1]; ov[2] = o[2]; ov[3] = o[3];
                *(u16x4*)(outT + (((size_t)(b * Cout + coL)) << 10) + rowb) = ov;
            }
        }
    }
}

// ---------------------------------------------------------------------------
// xc GEMM (64n x 64k, K=512) + fused x2, softmax, a_t write, asum atomics
// ---------------------------------------------------------------------------
__global__ __launch_bounds__(256)
void gemm_xc(const u16* __restrict__ e, const u16* __restrict__ cwb,
             const float* __restrict__ scale, const float* __restrict__ c2,
             u16* __restrict__ a_t, float* __restrict__ asum)
{
    const int b  = blockIdx.y;
    const int n0 = blockIdx.x * 64;
    const int t    = threadIdx.x;
    const int lane = t & 63;
    const int w    = t >> 6;
    const int wr = w >> 1, wc = w & 1;
    const int lhi = lane >> 4, llo = lane & 15;

    __shared__ __align__(16) char smem[16640];       // As(4KB)+Bs(4KB) | sm[64][65] f32
    u16* As = (u16*)smem;
    u16* Bs = (u16*)(smem + 4096);
    float (*sm)[65] = (float(*)[65])smem;
    __shared__ float x2s[64], pmax[64][4], psum[64][4], sc_s[64], c2_s[64];
    if (t < 64) { sc_s[t] = scale[t]; c2_s[t] = c2[t]; }

    f32x4 acc[2][2];
#pragma unroll
    for (int i = 0; i < 2; ++i)
#pragma unroll
        for (int j = 0; j < 2; ++j) acc[i][j] = (f32x4){0.f, 0.f, 0.f, 0.f};
    float x2p = 0.f;
    const int aBase = lhi * 64 + wr * 32 + llo;
    const int bBase = lhi * 64 + wc * 32 + llo;
    const int xr = w * 16 + (lane >> 2);   // row this lane accumulates x2 for
    const int xg = lane & 3;

    const int g = t >> 6, r = t & 63;
    for (int k0 = 0; k0 < 512; k0 += 32) {
        gload16(e + ((size_t)((b << 10) + n0 + r)) * 512 + k0 + g * 8, &As[t * 8]);
        gload16(cwb + (size_t)r * 512 + k0 + g * 8, &Bs[t * 8]);
        __syncthreads();
        {   // x2 partial from staged A tile
            u16x8 vv = *(const u16x8*)&As[(xg * 64 + xr) * 8];
#pragma unroll
            for (int j = 0; j < 8; ++j) { float f = bf2f(vv[j]); x2p = fmaf(f, f, x2p); }
        }
        const bf16x8* Av = (const bf16x8*)As;
        const bf16x8* Bv = (const bf16x8*)Bs;
        bf16x8 af[2], bfr[2];
#pragma unroll
        for (int m = 0; m < 2; ++m)  af[m]  = Av[aBase + m * 16];
#pragma unroll
        for (int nf = 0; nf < 2; ++nf) bfr[nf] = Bv[bBase + nf * 16];
#pragma unroll
        for (int m = 0; m < 2; ++m)
#pragma unroll
            for (int nf = 0; nf < 2; ++nf)
                acc[m][nf] = __builtin_amdgcn_mfma_f32_16x16x32_bf16(af[m], bfr[nf], acc[m][nf], 0, 0, 0);
        __syncthreads();
    }
    // x2 reduce over the 4 k-groups (same wave)
    float xs = x2p + __shfl_xor(x2p, 1, 64);
    xs += __shfl_xor(xs, 2, 64);
    if ((lane & 3) == 0) x2s[xr] = xs;
    __syncthreads();
    // sl2 -> sm (LDS reused; staging dead)
#pragma unroll
    for (int m = 0; m < 2; ++m)
#pragma unroll
        for (int nf = 0; nf < 2; ++nf)
#pragma unroll
            for (int q = 0; q < 4; ++q) {
                int rr = wr * 32 + m * 16 + lhi * 4 + q;
                int cc = wc * 32 + nf * 16 + llo;
                sm[rr][cc] = sc_s[cc] * (x2s[rr] - 2.f * acc[m][nf][q] + c2_s[cc]);
            }
    __syncthreads();
    // softmax: 4 threads per row, 16 k each
    const int gq = t >> 6;
    float vloc[16];
    float pm = -1e30f;
#pragma unroll
    for (int j = 0; j < 16; ++j) { float v = sm[r][gq * 16 + j]; vloc[j] = v; pm = fmaxf(pm, v); }
    pmax[r][gq] = pm;
    __syncthreads();
    float mm = fmaxf(fmaxf(pmax[r][0], pmax[r][1]), fmaxf(pmax[r][2], pmax[r][3]));
    float ps = 0.f;
#pragma unroll
    for (int j = 0; j < 16; ++j) { float p = __expf(vloc[j] - mm); vloc[j] = p; ps += p; }
    psum[r][gq] = ps;
    __syncthreads();
    float inv = 1.f / (psum[r][0] + psum[r][1] + psum[r][2] + psum[r][3]);
#pragma unroll
    for (int j = 0; j < 16; ++j) {
        int k = gq * 16 + j;
        float av = vloc[j] * inv;
        a_t[((size_t)((b << 6) + k) << 10) + n0 + r] = f2bf(av);
        sm[r][k] = av;
    }
    __syncthreads();
    // asum: column sums + atomics
    const int kk = t & 63, rg = t >> 6;
    float pa = 0.f;
#pragma unroll
    for (int j = 0; j < 16; ++j) pa += sm[rg * 16 + j][kk];
    atomicAdd(&asum[(b << 6) + kk], pa);
}

// ---------------------------------------------------------------------------
// enc MFMA: out(64k x 64c tile), K=1024 pixels; epilogue asum/BN/relu/mean_k
// ---------------------------------------------------------------------------
__global__ __launch_bounds__(256)
void enc_mfma(const u16* __restrict__ a_t, const u16* __restrict__ e_t,
              const float* __restrict__ cw, const float* __restrict__ asum,
              const float* __restrict__ sK, const float* __restrict__ bK,
              float* __restrict__ en)
{
    const int b  = blockIdx.y;
    const int c0 = blockIdx.x * 64;
    const int t    = threadIdx.x;
    const int lane = t & 63;
    const int w    = t >> 6;
    const int lhi = lane >> 4, llo = lane & 15;
    __shared__ __align__(16) u16 As[2048];
    __shared__ __align__(16) u16 Bs[2048];
    f32x4 acc[4];
#pragma unroll
    for (int i = 0; i < 4; ++i) acc[i] = (f32x4){0.f, 0.f, 0.f, 0.f};
    const int aBase = lhi * 64 + llo;
    const int bBase = lhi * 64 + w * 16 + llo;
    const int g = t >> 6, r = t & 63;

    for (int n0 = 0; n0 < NPIX; n0 += 32) {
        gload16(a_t + ((size_t)((b << 6) + r) << 10) + n0 + g * 8, &As[t * 8]);
        gload16(e_t + ((size_t)((b << 9) + c0 + r) << 10) + n0 + g * 8, &Bs[t * 8]);
        __syncthreads();
        const bf16x8* Av = (const bf16x8*)As;
        const bf16x8* Bv = (const bf16x8*)Bs;
        bf16x8 bfr = Bv[bBase];
#pragma unroll
        for (int m = 0; m < 4; ++m)
            acc[m] = __builtin_amdgcn_mfma_f32_16x16x32_bf16(Av[aBase + m * 16], bfr, acc[m], 0, 0, 0);
        __syncthreads();
    }
    const int c = c0 + w * 16 + llo;
    float s = 0.f;
#pragma unroll
    for (int m = 0; m < 4; ++m)
#pragma unroll
        for (int q = 0; q < 4; ++q) {
            int k = m * 16 + lhi * 4 + q;
            float v = acc[m][q] - asum[(b << 6) + k] * cw[((size_t)k << 9) + c];
            v = fmaxf(fmaf(v, sK[k], bK[k]), 0.f);
            s += v;
        }
    s += __shfl_xor(s, 16, 64);
    s += __shfl_xor(s, 32, 64);
    if (lane < 16) en[(size_t)(b << 9) + c] = s * (1.f / 64.f);
}

// ---------------- NCHW f32 -> NHWC bf16 ----------------
__global__ __launch_bounds__(256)
void tr_in_k(const float* __restrict__ x, u16* __restrict__ xbf)
{
    __shared__ float tile[64][65];
    int b = blockIdx.z, n0 = blockIdx.x * 64, c0 = blockIdx.y * 64, t = threadIdx.x;
#pragma unroll
    for (int q = 0; q < 16; ++q) {
        int idx = t + 256 * q;
        int c = idx >> 6, n = idx & 63;
        tile[c][n] = x[((size_t)((b << 9) + c0 + c) << 10) + n0 + n];
    }
    __syncthreads();
#pragma unroll
    for (int q = 0; q < 16; ++q) {
        int idx = t + 256 * q;
        int nn = idx >> 6, cc = idx & 63;
        xbf[((size_t)((b << 10) + n0 + nn) << 9) + c0 + cc] = f2bf(tile[cc][nn]);
    }
}

// ---------------- final: out(NCHW f32) = relu(xb_bf16*(1+gam)) ----------------
__global__ __launch_bounds__(256)
void final_tr_k(const u16* __restrict__ xb, const float* __restrict__ gam,
                float* __restrict__ out)
{
    __shared__ float tile[64][65];
    int b = blockIdx.z, n0 = blockIdx.x * 64, c0 = blockIdx.y * 64, t = threadIdx.x;
#pragma unroll
    for (int q = 0; q < 16; ++q) {
        int idx = t + 256 * q;
        int n = idx >> 6, c = idx & 63;
        float gm = 1.f + gam[(b << 9) + c0 + c];
        float v = bf2f(xb[((size_t)((b << 10) + n0 + n) << 9) + c0 + c]) * gm;
        tile[n][c] = fmaxf(v, 0.f);
    }
    __syncthreads();
#pragma unroll
    for (int q = 0; q < 16; ++q) {
        int idx = t + 256 * q;
        int cc = idx >> 6, nn = idx & 63;
        out[((size_t)((b << 9) + c0 + cc) << 10) + n0 + nn] = tile[nn][cc];
    }
}

// ---------------- SE gate ----------------
__global__ __launch_bounds__(256)
void gam_k(const float* __restrict__ en, const float* __restrict__ fcw,
           const float* __restrict__ fcb, float* __restrict__ gam)
{
    int b = blockIdx.x;
    int c = blockIdx.y * 256 + threadIdx.x;
    __shared__ float es[C];
    es[threadIdx.x]       = en[(size_t)b * C + threadIdx.x];
    es[threadIdx.x + 256] = en[(size_t)b * C + threadIdx.x + 256];
    __syncthreads();
    float s = fcb[c];
    const float* wp = fcw + (size_t)c * C;
    for (int i = 0; i < C; i += 4) {
        float4 wv = ld4(wp + i);
        s = fmaf(es[i], wv.x, s);
        s = fmaf(es[i + 1], wv.y, s);
        s = fmaf(es[i + 2], wv.z, s);
        s = fmaf(es[i + 3], wv.w, s);
    }
    gam[(size_t)b * C + c] = 1.f / (1.f + __expf(-s));
}

// ---------------- merged weight prep ----------------
__global__ __launch_bounds__(256)
void prep_all_k(const float* c1w, const float* bn1g, const float* bn2g,
                const float* c2w, const float* c3w, const float* bn3g,
                const float* bn3b, const float* rcw, const float* rbng,
                const float* rbnb, const float* lvcw, const float* lvcbng,
                const float* enbng, const float* cw,
                u16* c1b, u16* w2b, u16* wcatb, u16* lvcb, u16* cwb,
                float* s1, float* s2, float* slvc, float* bcat,
                float* sK, float* c2, float* asum, u16* zbuf)
{
    const float invCB  = rsqrtf(1.f + 1e-6f);
    const float invLVC = rsqrtf(1.f + 1e-5f);
    long id = (long)blockIdx.x * 256 + threadIdx.x;
    if (id < 327680) {                       // wcatb (512co x 640k)
        int co = (int)(id / 640), k = (int)(id % 640);
        float v = (k < 128) ? c3w[co * 128 + k] * (bn3g[co] * invCB)
                            : rcw[co * 512 + (k - 128)] * (rbng[co] * invCB);
        wcatb[id] = f2bf(v);
        return;
    }
    id -= 327680;
    if (id < 147456) {                       // w2b (128co x 1152k)
        int co = (int)(id / 1152), k = (int)(id % 1152);
        int tap = k >> 7, ci = k & 127;
        w2b[id] = f2bf(c2w[co * 1152 + ci * 9 + tap]);
        return;
    }
    id -= 147456;
    if (id < 262144) { lvcb[id] = f2bf(lvcw[id]); return; }
    id -= 262144;
    if (id < 65536)  { c1b[id]  = f2bf(c1w[id]);  return; }
    id -= 65536;
    if (id < 32768)  { cwb[id]  = f2bf(cw[id]);   return; }
    id -= 32768;
    if (id < 2048)   { asum[id] = 0.f; return; }
    id -= 2048;
    if (id < 1024)   { zbuf[id] = 0;   return; }
    id -= 1024;
    if (id < 128) { s1[id] = bn1g[id] * invCB; return; }
    id -= 128;
    if (id < 128) { s2[id] = bn2g[id] * invCB; return; }
    id -= 128;
    if (id < 512) { slvc[id] = lvcbng[id] * invLVC; return; }
    id -= 512;
    if (id < 512) { bcat[id] = bn3b[id] + rbnb[id]; return; }
    id -= 512;
    if (id < 64)  { sK[id] = enbng[id] * invLVC; return; }
    id -= 64;
    if (id < 64) {
        float s = 0.f;
        for (int c = 0; c < C; ++c) s = fmaf(cw[id * C + c], cw[id * C + c], s);
        c2[id] = s;
    }
}

// ---------------------------------------------------------------------------
extern "C" void kernel_launch(void* const* d_in, const int* in_sizes, int n_in,
                              void* d_out, int out_size, void* d_ws, size_t ws_size,
                              hipStream_t stream)
{
    const float* x      = (const float*)d_in[0];
    const float* c1w    = (const float*)d_in[1];
    const float* bn1g   = (const float*)d_in[2];
    const float* bn1b   = (const float*)d_in[3];
    const float* c2w    = (const float*)d_in[4];
    const float* bn2g   = (const float*)d_in[5];
    const float* bn2b   = (const float*)d_in[6];
    const float* c3w    = (const float*)d_in[7];
    const float* bn3g   = (const float*)d_in[8];
    const float* bn3b   = (const float*)d_in[9];
    const float* rcw    = (const float*)d_in[10];
    const float* rbng   = (const float*)d_in[11];
    const float* rbnb   = (const float*)d_in[12];
    const float* lvcw   = (const float*)d_in[13];
    const float* lvcbng = (const float*)d_in[14];
    const float* lvcbnb = (const float*)d_in[15];
    const float* cw     = (const float*)d_in[16];
    const float* scale  = (const float*)d_in[17];
    const float* enbng  = (const float*)d_in[18];
    const float* enbnb  = (const float*)d_in[19];
    const float* fcw    = (const float*)d_in[20];
    const float* fcb    = (const float*)d_in[21];
    float* out = (float*)d_out;
    char* W = (char*)d_ws;

    // ---- workspace layout (bytes) ----
    u16*  xbf  = (u16*)(W);                 // 32MB (B,N,512) x in NHWC  [later: e]
    u16*  e_b  = xbf;
    u16*  h1   = (u16*)(W + 33554432);      // 8MB (B,N,128)   [later: a_t (4MB)]
    u16*  a_t  = h1;
    u16*  h2   = (u16*)(W + 41943040);      // 8MB (B,N,128)
    u16*  xb_b = (u16*)(W + 50331648);      // 32MB (B,N,512) bf16
    u16*  e_t  = (u16*)(W + 83886080);      // 32MB (B,512,N) bf16
    char* wb   = W + 117440512;             // weights region
    u16* c1b   = (u16*)(wb);                // 131072 B
    u16* w2b   = (u16*)(wb + 131072);       // 294912 B
    u16* wcatb = (u16*)(wb + 425984);       // 655360 B
    u16* lvcb  = (u16*)(wb + 1081344);      // 524288 B
    u16* cwb   = (u16*)(wb + 1605632);      // 65536 B
    float* fb  = (float*)(wb + 1671168);
    float* asum = fb;                       // 2048
    float* en   = fb + 2048;                // 16384
    float* gam  = fb + 18432;               // 16384
    float* s1   = fb + 34816;               // 128
    float* s2   = s1 + 128;
    float* slvc = s2 + 128;
    float* bcat = slvc + 512;
    float* sK   = bcat + 512;
    float* c2   = sK + 64;
    u16* zbuf   = (u16*)(c2 + 64);          // 2KB

    // prep (single launch)
    prep_all_k<<<3282, 256, 0, stream>>>(c1w, bn1g, bn2g, c2w, c3w, bn3g, bn3b,
                                         rcw, rbng, rbnb, lvcw, lvcbng, enbng, cw,
                                         c1b, w2b, wcatb, lvcb, cwb,
                                         s1, s2, slvc, bcat, sK, c2, asum, zbuf);

    // x (NCHW f32) -> xbf (NHWC bf16)
    tr_in_k<<<dim3(16, 8, 32), 256, 0, stream>>>(x, xbf);

    // conv1 + bn1 + relu -> h1
    gemm_mfma<0, 64, true, false><<<dim3(16, 1, 32), 256, 0, stream>>>(
        xbf, nullptr, c1b, h1, nullptr, s1, bn1b, zbuf, 512, 128);
    // conv2 (3x3) + bn2 + relu -> h2
    gemm_mfma<1, 64, true, false><<<dim3(16, 1, 32), 256, 0, stream>>>(
        h1, nullptr, w2b, h2, nullptr, s2, bn2b, zbuf, 1152, 128);
    // conv3+bn3 + residual+bn (concat-K) + relu -> xb_b
    gemm_mfma<2, 128, true, false><<<dim3(8, 4, 32), 256, 0, stream>>>(
        h2, xbf, wcatb, xb_b, nullptr, nullptr, bcat, zbuf, 640, 512);
    // lvc + bn + relu -> e (NHWC) AND e_t (NCHW) via dual-write epilogue
    gemm_mfma<0, 128, true, true><<<dim3(8, 4, 32), 256, 0, stream>>>(
        xb_b, nullptr, lvcb, e_b, e_t, slvc, lvcbnb, zbuf, 512, 512);
    // xc GEMM + x2 + softmax + a_t + asum
    gemm_xc<<<dim3(16, 32), 256, 0, stream>>>(e_b, cwb, scale, c2, a_t, asum);
    // enc (MFMA) + BN + relu + mean_k -> en
    enc_mfma<<<dim3(8, 32), 256, 0, stream>>>(a_t, e_t, cw, asum, sK, enbnb, en);
    // SE gate
    gam_k<<<dim3(32, 2), 256, 0, stream>>>(en, fcw, fcb, gam);
    // final: out(NCHW f32) = relu(xb*(1+gam))
    final_tr_k<<<dim3(16, 8, 32), 256, 0, stream>>>(xb_b, gam, out);
}